// Round 5
// baseline (5345.315 us; speedup 1.0000x reference)
//
#include <hip/hip_runtime.h>
#include <math.h>

#define Bn 64
#define Hn 1024
#define En 512
#define Sn 512
#define RING 32
#define NBLK 256

typedef _Float16 f16;
typedef _Float16 half8 __attribute__((ext_vector_type(8)));
typedef float f32x4 __attribute__((ext_vector_type(4)));
typedef unsigned long long u64;
typedef u64 u64x2 __attribute__((ext_vector_type(2)));

// ============================================================================
// Round 11: round-10 kernel (passed, 264 us/chunk) with ONE change:
//   dataflow gating instead of a full grid barrier.
//   Wave kq consumes h k-columns kq*256..kq*256+255, produced by blocks
//   bb in [kq*64, (kq+1)*64). Gate each wave on a per-quarter producer
//   counter (4 sub-lines x 16 producers each, 128 B apart):
//     producer: store h (device scope) -> vmcnt(0) -> syncthreads ->
//               tid==0 adds to cnt[bb>>6][(bb>>4)&3]
//     consumer: wave kq polls sum of quarter kq's 4 sub-lines >= 64*T
//   Double buffer stays safe: a block reaches iteration T only after all
//   blocks finished T-1 (loads consumed before store, by data dep), so
//   writing H[T+1] over H[T-1] cannot race any reader. Counters monotonic
//   across the 16 chunk launches (gates pre-satisfied at launch entry).
// Everything else identical to round 10 (targeted coherence):
//   - hF loads/stores: __hip_atomic_{load,store}(RELAXED, AGENT) (MALL)
//   - gx block-local, plain loads/stores
//   - Wh weights in LDS; c in registers across the chunk
// ============================================================================

__global__ __launch_bounds__(256) void wpack_kernel(
    const float* __restrict__ Whi_, const float* __restrict__ Whf_,
    const float* __restrict__ Whg_, const float* __restrict__ Who_,
    const float* __restrict__ Wxi_, const float* __restrict__ Wxf_,
    const float* __restrict__ Wxg_, const float* __restrict__ Wxo_,
    f16* __restrict__ wpHi, f16* __restrict__ wpLo)
{
    int t = blockIdx.x * 256 + threadIdx.x;   // 786432 = 256*48*64
    int lane = t & 63;
    int rest = t >> 6;
    int kc = rest % 48;
    int bb = rest / 48;
    int n = lane & 15, g = n >> 2, du = n & 3;
    int u = bb * 4 + du;
    int klo = (lane >> 4) << 3;
    const float* Wh = (g == 0 ? Whi_ : g == 1 ? Whf_ : g == 2 ? Whg_ : Who_);
    const float* Wx = (g == 0 ? Wxi_ : g == 1 ? Wxf_ : g == 2 ? Wxg_ : Wxo_);
    const float* src = (kc < 32) ? (Wh + (size_t)u * Hn + kc * 32 + klo)
                                 : (Wx + (size_t)u * En + (kc - 32) * 32 + klo);
    float4 v0 = ((const float4*)src)[0];
    float4 v1 = ((const float4*)src)[1];
    float w[8] = {v0.x, v0.y, v0.z, v0.w, v1.x, v1.y, v1.z, v1.w};
    #pragma unroll
    for (int j = 0; j < 8; ++j) {
        f16 hi = (f16)w[j];
        float lo = (w[j] - (float)hi) * 2048.0f;
        wpHi[(size_t)t * 8 + j] = hi;
        wpLo[(size_t)t * 8 + j] = (f16)lo;
    }
}

__global__ __launch_bounds__(256) void epack_kernel(
    const int* __restrict__ x, const float* __restrict__ emb,
    f16* __restrict__ eF)
{
    int t = blockIdx.x * 256 + threadIdx.x;   // 2097152 = 512*16*4*64
    int lane = t & 63;
    int q = t >> 6;
    int mt = q & 3; q >>= 2;
    int kc2 = q & 15;
    int s = q >> 4;
    int b = mt * 16 + (lane & 15);
    int tok = x[b * Sn + s];
    int k = kc2 * 32 + ((lane >> 4) << 3);
    const float* src = emb + (size_t)tok * En + k;
    float4 v0 = ((const float4*)src)[0];
    float4 v1 = ((const float4*)src)[1];
    f16* dst = eF + (size_t)t * 8;
    dst[0] = (f16)v0.x; dst[1] = (f16)v0.y; dst[2] = (f16)v0.z; dst[3] = (f16)v0.w;
    dst[4] = (f16)v1.x; dst[5] = (f16)v1.y; dst[6] = (f16)v1.z; dst[7] = (f16)v1.w;
}

// ---------------- fallback gx kernel (round-6 proven) ----------------
__global__ __launch_bounds__(256) void gx_chunk_kernel(
    const half8* __restrict__ eF,
    const half8* __restrict__ wpHi, const half8* __restrict__ wpLo,
    float* __restrict__ gx, int chunk)
{
    int lane = threadIdx.x & 63;
    int id = blockIdx.x * 4 + (threadIdx.x >> 6);
    int sc = id >> 8;            // 0..31
    int bb = id & 255;
    int s = chunk * RING + sc;

    const half8* eFs = eF + (size_t)s * 4096 + lane;
    const half8* bH = wpHi + ((size_t)(bb * 48 + 32)) * 64 + lane;
    const half8* bL = wpLo + ((size_t)(bb * 48 + 32)) * 64 + lane;

    f32x4 aH[4], aL[4];
    #pragma unroll
    for (int mt = 0; mt < 4; ++mt) { aH[mt] = (f32x4)0.0f; aL[mt] = (f32x4)0.0f; }

    for (int kcx = 0; kcx < 16; ++kcx) {
        half8 bh = bH[(size_t)kcx * 64];
        half8 bl = bL[(size_t)kcx * 64];
        #pragma unroll
        for (int mt = 0; mt < 4; ++mt) {
            half8 a = eFs[(size_t)((kcx * 4 + mt) * 64)];
            aH[mt] = __builtin_amdgcn_mfma_f32_16x16x32_f16(a, bh, aH[mt], 0, 0, 0);
            aL[mt] = __builtin_amdgcn_mfma_f32_16x16x32_f16(a, bl, aL[mt], 0, 0, 0);
        }
    }

    int n = lane & 15, g = n >> 2, du = n & 3;
    int col = (g << 10) + bb * 4 + du;
    float* g0 = gx + (size_t)sc * (Bn * 4096) + col;
    #pragma unroll
    for (int mt = 0; mt < 4; ++mt) {
        #pragma unroll
        for (int r = 0; r < 4; ++r) {
            int b = mt * 16 + ((lane >> 4) << 2) + r;
            g0[(size_t)b * 4096] = aH[mt][r] + aL[mt][r] * (1.0f / 2048.0f);
        }
    }
}

// ---------------- fallback per-step kernel (round-6 proven) ----------------
template<bool USE_GX>
__global__ __launch_bounds__(1024) void step_kernel(
    const f16* __restrict__ hFin, f16* __restrict__ hFout,
    const half8* __restrict__ eF,
    const half8* __restrict__ wpHi, const half8* __restrict__ wpLo,
    const float* __restrict__ gx,
    const float* __restrict__ bi, const float* __restrict__ bf,
    const float* __restrict__ bg, const float* __restrict__ bo,
    float* __restrict__ c, float* __restrict__ hFinal, int s)
{
    __shared__ float preW[16][256];       // 16 KB

    const int tid  = threadIdx.x;
    const int lane = tid & 63;
    const int wv   = tid >> 6;
    const int mt   = wv & 3;
    const int kq   = wv >> 2;
    const int bb   = blockIdx.x;

    const half8* hin = (const half8*)hFin + lane;
    const half8* bHb = wpHi + (size_t)(bb * 48) * 64 + lane;
    const half8* bLb = wpLo + (size_t)(bb * 48) * 64 + lane;

    f32x4 accH = {0.f, 0.f, 0.f, 0.f};
    f32x4 accL = {0.f, 0.f, 0.f, 0.f};

    if (USE_GX) {
        #pragma unroll
        for (int i = 0; i < 8; ++i) {
            int kc = kq * 8 + i;
            half8 a  = hin[(size_t)((kc * 4 + mt) * 64)];
            half8 bh = bHb[(size_t)kc * 64];
            half8 bl = bLb[(size_t)kc * 64];
            accH = __builtin_amdgcn_mfma_f32_16x16x32_f16(a, bh, accH, 0, 0, 0);
            accL = __builtin_amdgcn_mfma_f32_16x16x32_f16(a, bl, accL, 0, 0, 0);
        }
    } else {
        const half8* eFs = eF + (size_t)s * 4096 + lane;
        #pragma unroll
        for (int i = 0; i < 12; ++i) {
            int kc = kq * 12 + i;
            half8 a = (kc < 32) ? hin[(size_t)((kc * 4 + mt) * 64)]
                                : eFs[(size_t)(((kc - 32) * 4 + mt) * 64)];
            half8 bh = bHb[(size_t)kc * 64];
            half8 bl = bLb[(size_t)kc * 64];
            accH = __builtin_amdgcn_mfma_f32_16x16x32_f16(a, bh, accH, 0, 0, 0);
            accL = __builtin_amdgcn_mfma_f32_16x16x32_f16(a, bl, accL, 0, 0, 0);
        }
    }

    f32x4 v;
    #pragma unroll
    for (int r = 0; r < 4; ++r) v[r] = accH[r] + accL[r] * (1.0f / 2048.0f);
    *(f32x4*)&preW[wv][lane * 4] = v;
    __syncthreads();

    if (tid < 256) {
        const int bcell = tid >> 2, ducell = tid & 3;
        const int colcell = bb * 4 + ducell;          // h-unit 0..1023
        const int msub = bcell & 15, mtp = bcell >> 4;
        const int base_i = ((msub >> 2) * 16) * 4 + (msub & 3);
        float sg_[4];
        #pragma unroll
        for (int g = 0; g < 4; ++g) {
            int idx = base_i + (g * 4 + ducell) * 4;
            sg_[g] = preW[0 * 4 + mtp][idx] + preW[1 * 4 + mtp][idx]
                   + preW[2 * 4 + mtp][idx] + preW[3 * 4 + mtp][idx];
        }
        float si = sg_[0] + bi[colcell];
        float sf = sg_[1] + bf[colcell];
        float sg = sg_[2] + bg[colcell];
        float so = sg_[3] + bo[colcell];
        if (USE_GX) {
            const float* gr = gx + ((size_t)(s & (RING - 1)) * Bn + bcell) * 4096;
            si += gr[colcell];        sf += gr[1024 + colcell];
            sg += gr[2048 + colcell]; so += gr[3072 + colcell];
        }
        float it = 1.f / (1.f + expf(-si));
        float ft = 1.f / (1.f + expf(-sf));
        float gt = tanhf(sg);
        float ot = 1.f / (1.f + expf(-so));
        int gi = bcell * Hn + colcell;
        float cn = ft * c[gi] + it * gt;
        c[gi] = cn;
        float hn = ot * tanhf(cn);
        int kch = colcell >> 5, dk = colcell & 31;
        int lp  = ((dk >> 3) << 4) | (bcell & 15);
        int mtp2 = bcell >> 4;
        hFout[((size_t)((kch * 4 + mtp2) * 64 + lp)) * 8 + (dk & 7)] = (f16)hn;
        if (s == Sn - 1) hFinal[gi] = hn;
    }
}

// ---------------- per-chunk persistent cooperative kernel ----------------
// cnt layout (uint32 indices): quarter q sub-line j at q*128 + j*32
// (q=0..3, j=0..3; 16 lines, 128 B apart). Monotonic across launches.
__global__ __launch_bounds__(1024) void steps_chunk_coop(
    f16* __restrict__ hF,                 // 2 x 65536 f16 (double buffer)
    const half8* __restrict__ eF,
    const half8* __restrict__ wpHi, const half8* __restrict__ wpLo,
    float* __restrict__ gx,
    const float* __restrict__ bi, const float* __restrict__ bf,
    const float* __restrict__ bg, const float* __restrict__ bo,
    float* __restrict__ c, float* __restrict__ hFinal,
    unsigned* __restrict__ cntArr, int chunk)
{
    __shared__ alignas(16) f16 wHs[32 * 512];   // 32 KB  Wh hi, kc 0..31
    __shared__ alignas(16) f16 wLs[32 * 512];   // 32 KB  Wh lo
    __shared__ float preW[16][256];             // 16 KB

    const int tid  = threadIdx.x;
    const int lane = tid & 63;
    const int wv   = tid >> 6;
    const int mt   = wv & 3;
    const int kq   = wv >> 2;
    const int bb   = blockIdx.x;

    // ---- stage this block's Wh weights into LDS ----
    {
        const half8* srcH = wpHi + (size_t)(bb * 48) * 64;
        const half8* srcL = wpLo + (size_t)(bb * 48) * 64;
        half8* dH = (half8*)wHs;
        half8* dL = (half8*)wLs;
        #pragma unroll
        for (int i = 0; i < 2; ++i) {         // 2048 half8 per buffer
            dH[tid + i * 1024] = srcH[tid + i * 1024];
            dL[tid + i * 1024] = srcL[tid + i * 1024];
        }
    }

    // ---- gx prologue: wave wv computes sc = 2*wv, 2*wv+1 for this bb ----
    {
        const half8* bH = wpHi + ((size_t)(bb * 48 + 32)) * 64 + lane;
        const half8* bL = wpLo + ((size_t)(bb * 48 + 32)) * 64 + lane;
        #pragma unroll
        for (int t2 = 0; t2 < 2; ++t2) {
            int sc = wv * 2 + t2;
            int s = chunk * RING + sc;
            const half8* eFs = eF + (size_t)s * 4096 + lane;
            f32x4 aH[4], aL[4];
            #pragma unroll
            for (int m2 = 0; m2 < 4; ++m2) { aH[m2] = (f32x4)0.0f; aL[m2] = (f32x4)0.0f; }
            for (int kcx = 0; kcx < 16; ++kcx) {
                half8 bh = bH[(size_t)kcx * 64];
                half8 bl = bL[(size_t)kcx * 64];
                #pragma unroll
                for (int m2 = 0; m2 < 4; ++m2) {
                    half8 a = eFs[(size_t)((kcx * 4 + m2) * 64)];
                    aH[m2] = __builtin_amdgcn_mfma_f32_16x16x32_f16(a, bh, aH[m2], 0, 0, 0);
                    aL[m2] = __builtin_amdgcn_mfma_f32_16x16x32_f16(a, bl, aL[m2], 0, 0, 0);
                }
            }
            int n = lane & 15, g = n >> 2, du = n & 3;
            int col = (g << 10) + bb * 4 + du;
            float* g0 = gx + (size_t)sc * (Bn * 4096) + col;
            #pragma unroll
            for (int m2 = 0; m2 < 4; ++m2) {
                #pragma unroll
                for (int r = 0; r < 4; ++r) {
                    int b = m2 * 16 + ((lane >> 4) << 2) + r;
                    g0[(size_t)b * 4096] = aH[m2][r] + aL[m2][r] * (1.0f / 2048.0f);
                }
            }
        }
    }

    // ---- per-cell persistent state ----
    float creg = 0.f, bi_r = 0.f, bf_r = 0.f, bg_r = 0.f, bo_r = 0.f;
    int bcell = 0, ducell = 0, colcell = 0, gi = 0, mtp = 0, base_i = 0;
    int kch = 0, dk = 0, lp = 0;
    if (tid < 256) {
        bcell = tid >> 2; ducell = tid & 3;
        colcell = bb * 4 + ducell;
        gi = bcell * Hn + colcell;
        int msub = bcell & 15; mtp = bcell >> 4;
        base_i = ((msub >> 2) * 16) * 4 + (msub & 3);
        creg = c[gi];
        bi_r = bi[colcell]; bf_r = bf[colcell];
        bg_r = bg[colcell]; bo_r = bo[colcell];
        kch = colcell >> 5; dk = colcell & 31;
        lp  = ((dk >> 3) << 4) | (bcell & 15);
    }

    __syncthreads();   // gx prologue + LDS staging complete

    const half8* wHl = (const half8*)wHs + lane;
    const half8* wLl = (const half8*)wLs + lane;

    // this wave's quarter gate: 4 sub-lines at kq*128 + {0,32,64,96}
    const unsigned* qc = cntArr + ((unsigned)kq << 7);
    // this block's arrival slot
    unsigned* myslot = cntArr + (((unsigned)(bb >> 6)) << 7)
                              + (((unsigned)(bb >> 4) & 3u) << 5);

    #pragma unroll 1
    for (int sc = 0; sc < RING; ++sc) {
        const int s = chunk * RING + sc;
        const f16* hbase = hF + (size_t)(s & 1) * 65536;
        f16* hout = hF + (size_t)((s + 1) & 1) * 65536;

        // ---- dataflow gate: wait for this wave's producer quarter ----
        {
            const unsigned need = 64u * (unsigned)s;
            if (need) {
                while (true) {
                    unsigned s0 = __hip_atomic_load(qc, __ATOMIC_RELAXED,
                                                    __HIP_MEMORY_SCOPE_AGENT);
                    unsigned s1 = __hip_atomic_load(qc + 32, __ATOMIC_RELAXED,
                                                    __HIP_MEMORY_SCOPE_AGENT);
                    unsigned s2 = __hip_atomic_load(qc + 64, __ATOMIC_RELAXED,
                                                    __HIP_MEMORY_SCOPE_AGENT);
                    unsigned s3 = __hip_atomic_load(qc + 96, __ATOMIC_RELAXED,
                                                    __HIP_MEMORY_SCOPE_AGENT);
                    if (s0 + s1 + s2 + s3 >= need) break;
                    __builtin_amdgcn_s_sleep(1);
                }
            }
        }

        // gx loads (plain: same block wrote them through this CU's L1)
        float gxi = 0.f, gxf = 0.f, gxg = 0.f, gxo = 0.f;
        if (tid < 256) {
            const float* gr = gx + ((size_t)sc * Bn + bcell) * 4096 + colcell;
            gxi = gr[0];    gxf = gr[1024];
            gxg = gr[2048]; gxo = gr[3072];
        }

        // hF fragment loads: device-scope relaxed atomics (bypass stale
        // L1/L2, served from MALL where other blocks' stores landed)
        half8 afr[8];
        #pragma unroll
        for (int i = 0; i < 8; ++i) {
            const int kc = kq * 8 + i;
            const u64* p = (const u64*)(hbase
                + ((size_t)((kc * 4 + mt) * 64 + lane)) * 8);
            u64x2 u;
            u.x = __hip_atomic_load(p, __ATOMIC_RELAXED,
                                    __HIP_MEMORY_SCOPE_AGENT);
            u.y = __hip_atomic_load(p + 1, __ATOMIC_RELAXED,
                                    __HIP_MEMORY_SCOPE_AGENT);
            afr[i] = __builtin_bit_cast(half8, u);
        }

        f32x4 accH = {0.f, 0.f, 0.f, 0.f};
        f32x4 accL = {0.f, 0.f, 0.f, 0.f};
        #pragma unroll
        for (int i = 0; i < 8; ++i) {
            const int kc = kq * 8 + i;
            half8 bh = wHl[(size_t)kc * 64];
            half8 bl = wLl[(size_t)kc * 64];
            accH = __builtin_amdgcn_mfma_f32_16x16x32_f16(afr[i], bh, accH, 0, 0, 0);
            accL = __builtin_amdgcn_mfma_f32_16x16x32_f16(afr[i], bl, accL, 0, 0, 0);
        }
        f32x4 v;
        #pragma unroll
        for (int r = 0; r < 4; ++r) v[r] = accH[r] + accL[r] * (1.0f / 2048.0f);
        *(f32x4*)&preW[wv][lane * 4] = v;
        __syncthreads();

        if (tid < 256) {
            float sg_[4];
            #pragma unroll
            for (int g = 0; g < 4; ++g) {
                int idx = base_i + (g * 4 + ducell) * 4;
                sg_[g] = preW[mtp][idx] + preW[4 + mtp][idx]
                       + preW[8 + mtp][idx] + preW[12 + mtp][idx];
            }
            float si = sg_[0] + bi_r + gxi;
            float sf = sg_[1] + bf_r + gxf;
            float sg = sg_[2] + bg_r + gxg;
            float so = sg_[3] + bo_r + gxo;
            float it = 1.f / (1.f + expf(-si));
            float ft = 1.f / (1.f + expf(-sf));
            float gt = tanhf(sg);
            float ot = 1.f / (1.f + expf(-so));
            float cn = ft * creg + it * gt;
            creg = cn;
            float hn = ot * tanhf(cn);
            // scatter into next step's A-frag layout, device-scope store
            union { f16 h; unsigned short u; } cv;
            cv.h = (f16)hn;
            unsigned short* paddr = (unsigned short*)(hout
                + ((size_t)((kch * 4 + mtp) * 64 + lp)) * 8 + (dk & 7));
            __hip_atomic_store(paddr, cv.u, __ATOMIC_RELAXED,
                               __HIP_MEMORY_SCOPE_AGENT);
            if (s == Sn - 1) hFinal[gi] = hn;
        }

        // ---- producer arrival (replaces grid barrier) ----
        asm volatile("s_waitcnt vmcnt(0)" ::: "memory");  // drain own stores
        __syncthreads();            // all waves' stores drained; preW consumed
        if (tid == 0)
            __hip_atomic_fetch_add(myslot, 1u, __ATOMIC_RELAXED,
                                   __HIP_MEMORY_SCOPE_AGENT);
    }

    if (tid < 256) c[gi] = creg;
}

// ---- tail ----
__global__ __launch_bounds__(256) void copy_hc(
    const float* __restrict__ h, const float* __restrict__ c,
    float* __restrict__ out)
{
    int i = blockIdx.x * 256 + threadIdx.x;
    out[128 + i] = h[i];
    out[128 + Bn * Hn + i] = c[i];
}

__global__ __launch_bounds__(64) void classifier(
    const float* __restrict__ h, const float* __restrict__ Vw,
    const float* __restrict__ Vb, float* __restrict__ out)
{
    int bid = blockIdx.x;
    int b = bid >> 1, n = bid & 1;
    int lane = threadIdx.x;
    float sum = 0.f;
    for (int k = lane; k < Hn; k += 64)
        sum += h[b * Hn + k] * Vw[n * Hn + k];
    #pragma unroll
    for (int off = 32; off > 0; off >>= 1)
        sum += __shfl_down(sum, off, 64);
    if (lane == 0)
        out[b * 2 + n] = sum + Vb[n];
}

// ======================= fallback (round-1 proven path) =======================

#define KT 128
#define KTP 132

__global__ __launch_bounds__(256) void lstm_step_fb(
    const int* __restrict__ x, const float* __restrict__ emb,
    const float* __restrict__ Wxi, const float* __restrict__ Wxf,
    const float* __restrict__ Wxg, const float* __restrict__ Wxo,
    const float* __restrict__ bi, const float* __restrict__ bf,
    const float* __restrict__ bg, const float* __restrict__ bo,
    const float* __restrict__ Whi, const float* __restrict__ Whf,
    const float* __restrict__ Whg, const float* __restrict__ Who,
    const float* __restrict__ h_in, const float* __restrict__ c_in,
    float* __restrict__ h_out, float* __restrict__ c_out, int s)
{
    __shared__ float sh[Bn][KTP];
    __shared__ float sw[16][KTP];
    const int tid = threadIdx.x;
    const int b = tid >> 2, j = tid & 3;
    const int cb = blockIdx.x * 4, col = cb + j;
    float acc0 = 0.f, acc1 = 0.f, acc2 = 0.f, acc3 = 0.f;

    for (int k0 = 0; k0 < En; k0 += KT) {
        for (int i = tid; i < Bn * (KT / 4); i += 256) {
            int bl = i >> 5, k4 = (i & 31) << 2;
            int tok = x[bl * Sn + s];
            *reinterpret_cast<float4*>(&sh[bl][k4]) =
                *reinterpret_cast<const float4*>(&emb[(size_t)tok * En + k0 + k4]);
        }
        for (int i = tid; i < 16 * (KT / 4); i += 256) {
            int r = i >> 5, k4 = (i & 31) << 2;
            const float* Wg = (r < 8) ? ((r < 4) ? Wxi : Wxf)
                                      : ((r < 12) ? Wxg : Wxo);
            *reinterpret_cast<float4*>(&sw[r][k4]) =
                *reinterpret_cast<const float4*>(&Wg[(size_t)(cb + (r & 3)) * En + k0 + k4]);
        }
        __syncthreads();
        #pragma unroll 8
        for (int k = 0; k < KT; k += 4) {
            float4 hv = *reinterpret_cast<const float4*>(&sh[b][k]);
            float4 w0 = *reinterpret_cast<const float4*>(&sw[j][k]);
            float4 w1 = *reinterpret_cast<const float4*>(&sw[4 + j][k]);
            float4 w2 = *reinterpret_cast<const float4*>(&sw[8 + j][k]);
            float4 w3 = *reinterpret_cast<const float4*>(&sw[12 + j][k]);
            acc0 += hv.x*w0.x + hv.y*w0.y + hv.z*w0.z + hv.w*w0.w;
            acc1 += hv.x*w1.x + hv.y*w1.y + hv.z*w1.z + hv.w*w1.w;
            acc2 += hv.x*w2.x + hv.y*w2.y + hv.z*w2.z + hv.w*w2.w;
            acc3 += hv.x*w3.x + hv.y*w3.y + hv.z*w3.z + hv.w*w3.w;
        }
        __syncthreads();
    }
    for (int k0 = 0; k0 < Hn; k0 += KT) {
        for (int i = tid; i < Bn * (KT / 4); i += 256) {
            int bl = i >> 5, k4 = (i & 31) << 2;
            *reinterpret_cast<float4*>(&sh[bl][k4]) =
                *reinterpret_cast<const float4*>(&h_in[(size_t)bl * Hn + k0 + k4]);
        }
        for (int i = tid; i < 16 * (KT / 4); i += 256) {
            int r = i >> 5, k4 = (i & 31) << 2;
            const float* Wg = (r < 8) ? ((r < 4) ? Whi : Whf)
                                      : ((r < 12) ? Whg : Who);
            *reinterpret_cast<float4*>(&sw[r][k4]) =
                *reinterpret_cast<const float4*>(&Wg[(size_t)(cb + (r & 3)) * Hn + k0 + k4]);
        }
        __syncthreads();
        #pragma unroll 8
        for (int k = 0; k < KT; k += 4) {
            float4 hv = *reinterpret_cast<const float4*>(&sh[b][k]);
            float4 w0 = *reinterpret_cast<const float4*>(&sw[j][k]);
            float4 w1 = *reinterpret_cast<const float4*>(&sw[4 + j][k]);
            float4 w2 = *reinterpret_cast<const float4*>(&sw[8 + j][k]);
            float4 w3 = *reinterpret_cast<const float4*>(&sw[12 + j][k]);
            acc0 += hv.x*w0.x + hv.y*w0.y + hv.z*w0.z + hv.w*w0.w;
            acc1 += hv.x*w1.x + hv.y*w1.y + hv.z*w1.z + hv.w*w1.w;
            acc2 += hv.x*w2.x + hv.y*w2.y + hv.z*w2.z + hv.w*w2.w;
            acc3 += hv.x*w3.x + hv.y*w3.y + hv.z*w3.z + hv.w*w3.w;
        }
        __syncthreads();
    }
    acc0 += bi[col]; acc1 += bf[col]; acc2 += bg[col]; acc3 += bo[col];
    float it = 1.f / (1.f + expf(-acc0));
    float ft = 1.f / (1.f + expf(-acc1));
    float gt = tanhf(acc2);
    float ot = 1.f / (1.f + expf(-acc3));
    float cn = ft * c_in[b * Hn + col] + it * gt;
    c_out[b * Hn + col] = cn;
    h_out[b * Hn + col] = ot * tanhf(cn);
}

// ======================= launcher =======================

extern "C" void kernel_launch(void* const* d_in, const int* in_sizes, int n_in,
                              void* d_out, int out_size, void* d_ws, size_t ws_size,
                              hipStream_t stream) {
    const int*   x   = (const int*)  d_in[0];
    const float* emb = (const float*)d_in[1];
    const float* Wxi = (const float*)d_in[2];
    const float* bi  = (const float*)d_in[3];
    const float* Whi = (const float*)d_in[4];
    const float* Wxf = (const float*)d_in[5];
    const float* bf  = (const float*)d_in[6];
    const float* Whf = (const float*)d_in[7];
    const float* Wxg = (const float*)d_in[8];
    const float* bg  = (const float*)d_in[9];
    const float* Whg = (const float*)d_in[10];
    const float* Wxo = (const float*)d_in[11];
    const float* bo  = (const float*)d_in[12];
    const float* Who = (const float*)d_in[13];
    const float* Vw  = (const float*)d_in[14];
    const float* Vb  = (const float*)d_in[15];
    float* out = (float*)d_out;

    // ws: [hF 256K][c 256K][h 256K][eF 32M][wpHi 12M][wpLo 12M][gx 32M][cnt 4K]
    const size_t szHF = (size_t)2 * 65536 * sizeof(f16);              // 256 KB
    const size_t szC  = (size_t)Bn * Hn * sizeof(float);              // 256 KB
    const size_t szEF = (size_t)Sn * 16 * 4 * 64 * 8 * sizeof(f16);   // 32 MB
    const size_t szWp = (size_t)256 * 48 * 64 * 8 * sizeof(f16);      // 12 MB
    const size_t szGx = (size_t)RING * Bn * 4096 * sizeof(float);     // 32 MB
    const size_t need_mid  = szHF + 2 * szC + szEF + 2 * szWp;
    const size_t need_gx   = need_mid + szGx;
    const size_t need_coop = need_gx + 4096;

    if (ws_size >= need_mid) {
        const bool haveGx   = (ws_size >= need_gx);
        const bool haveCoop = (ws_size >= need_coop);
        char* base = (char*)d_ws;
        f16*   hF   = (f16*)base;   base += szHF;
        float* c    = (float*)base; base += szC;
        float* h    = (float*)base; base += szC;
        f16*   eF   = (f16*)base;   base += szEF;
        f16*   wpHi = (f16*)base;   base += szWp;
        f16*   wpLo = (f16*)base;   base += szWp;
        float* gx   = (float*)base; base += szGx;
        unsigned* cnt = (unsigned*)base;

        hipMemsetAsync(d_ws, 0, szHF + szC, stream);   // hF both bufs + c
        if (haveCoop) hipMemsetAsync(cnt, 0, 4096, stream);  // gate counters
        wpack_kernel<<<dim3(3072), dim3(256), 0, stream>>>(
            Whi, Whf, Whg, Who, Wxi, Wxf, Wxg, Wxo, wpHi, wpLo);
        epack_kernel<<<dim3(8192), dim3(256), 0, stream>>>(x, emb, eF);

        if (haveGx) {
            bool coop = haveCoop;
            for (int chunk = 0; chunk < Sn / RING; ++chunk) {
                if (coop) {
                    f16* hFp = hF;
                    const half8* eF8   = (const half8*)eF;
                    const half8* wpHi8 = (const half8*)wpHi;
                    const half8* wpLo8 = (const half8*)wpLo;
                    float* gxp = gx;
                    const float* bip = bi; const float* bfp = bf;
                    const float* bgp = bg; const float* bop = bo;
                    float* cp = c; float* hp = h;
                    unsigned* cntp = cnt;
                    int ci = chunk;
                    void* args[] = { &hFp, &eF8, &wpHi8, &wpLo8, &gxp,
                                     &bip, &bfp, &bgp, &bop, &cp, &hp,
                                     &cntp, &ci };
                    hipError_t e = hipLaunchCooperativeKernel(
                        (const void*)steps_chunk_coop, dim3(NBLK), dim3(1024),
                        args, 0, stream);
                    if (e != hipSuccess) { coop = false; (void)hipGetLastError(); }
                }
                if (!coop) {
                    gx_chunk_kernel<<<dim3(2048), dim3(256), 0, stream>>>(
                        (const half8*)eF, (const half8*)wpHi, (const half8*)wpLo,
                        gx, chunk);
                    for (int sc = 0; sc < RING; ++sc) {
                        int s = chunk * RING + sc;
                        const f16* hin  = hF + (size_t)(s & 1) * 65536;
                        f16*       hout = hF + (size_t)((s + 1) & 1) * 65536;
                        step_kernel<true><<<dim3(256), dim3(1024), 0, stream>>>(
                            hin, hout, (const half8*)eF,
                            (const half8*)wpHi, (const half8*)wpLo,
                            gx, bi, bf, bg, bo, c, h, s);
                    }
                }
            }
        } else {
            for (int s = 0; s < Sn; ++s) {
                const f16* hin  = hF + (size_t)(s & 1) * 65536;
                f16*       hout = hF + (size_t)((s + 1) & 1) * 65536;
                step_kernel<false><<<dim3(256), dim3(1024), 0, stream>>>(
                    hin, hout, (const half8*)eF,
                    (const half8*)wpHi, (const half8*)wpLo,
                    (const float*)nullptr, bi, bf, bg, bo, c, h, s);
            }
        }
        copy_hc<<<dim3(Bn * Hn / 256), dim3(256), 0, stream>>>(h, c, out);
        classifier<<<dim3(Bn * 2), dim3(64), 0, stream>>>(h, Vw, Vb, out);
    } else {
        float* hA = (float*)d_ws;
        float* cA = hA + Bn * Hn;
        float* hB = cA + Bn * Hn;
        float* cB = hB + Bn * Hn;
        hipMemsetAsync(d_ws, 0, (size_t)2 * Bn * Hn * sizeof(float), stream);
        for (int s = 0; s < Sn; ++s) {
            const float* hi = (s & 1) ? hB : hA;
            const float* ci = (s & 1) ? cB : cA;
            float* ho = (s & 1) ? hA : hB;
            float* co = (s & 1) ? cA : cB;
            lstm_step_fb<<<dim3(Hn / 4), dim3(256), 0, stream>>>(
                x, emb, Wxi, Wxf, Wxg, Wxo, bi, bf, bg, bo,
                Whi, Whf, Whg, Who, hi, ci, ho, co, s);
        }
        copy_hc<<<dim3(Bn * Hn / 256), dim3(256), 0, stream>>>(hA, cA, out);
        classifier<<<dim3(Bn * 2), dim3(64), 0, stream>>>(hA, Vw, Vb, out);
    }
}

// Round 6
// 4255.748 us; speedup vs baseline: 1.2560x; 1.2560x over previous
//
#include <hip/hip_runtime.h>
#include <math.h>

#define Bn 64
#define Hn 1024
#define En 512
#define Sn 512
#define RING 32
#define NBLK 256

typedef _Float16 f16;
typedef _Float16 half8 __attribute__((ext_vector_type(8)));
typedef float f32x4 __attribute__((ext_vector_type(4)));
typedef unsigned long long u64;
typedef u64 u64x2 __attribute__((ext_vector_type(2)));

// ============================================================================
// Round 12: round-10 kernel (best: 264 us/chunk, 4578 total) with 3 local fixes:
//   1) FLAT parallel barrier: arrivals = 16 lines x 16 producers (as before);
//      poll by WAVE 0 ONLY: lanes load line (lane&15) in one vector load
//      (4 lanes/line coalesce), 4x shfl_xor gives every lane the 16-line sum.
//      Removes the master+go serial chain (~1 us of MALL hops).
//      Lesson from round-11 regression: pollers must be minimal (1 wave, not
//      1024 threads) and poll targets must not collide with producer RMWs.
//   2) gx prefetch: next step's gx loads issued before the poll (gx is
//      chunk-precomputed, independent of h) - latency hides under the wait.
//   3) coalesced h stores: pack 4 f16 via shfl_down, one 8 B device-scope
//      store per bcell (64 stores/block instead of 256 x 2 B scatter).
// Everything else identical to round 10 (targeted coherence):
//   - hF loads/stores: __hip_atomic_{load,store}(RELAXED, AGENT) (MALL)
//   - gx block-local, plain loads/stores
//   - Wh weights in LDS; c in registers across the chunk
// ============================================================================

__global__ __launch_bounds__(256) void wpack_kernel(
    const float* __restrict__ Whi_, const float* __restrict__ Whf_,
    const float* __restrict__ Whg_, const float* __restrict__ Who_,
    const float* __restrict__ Wxi_, const float* __restrict__ Wxf_,
    const float* __restrict__ Wxg_, const float* __restrict__ Wxo_,
    f16* __restrict__ wpHi, f16* __restrict__ wpLo)
{
    int t = blockIdx.x * 256 + threadIdx.x;   // 786432 = 256*48*64
    int lane = t & 63;
    int rest = t >> 6;
    int kc = rest % 48;
    int bb = rest / 48;
    int n = lane & 15, g = n >> 2, du = n & 3;
    int u = bb * 4 + du;
    int klo = (lane >> 4) << 3;
    const float* Wh = (g == 0 ? Whi_ : g == 1 ? Whf_ : g == 2 ? Whg_ : Who_);
    const float* Wx = (g == 0 ? Wxi_ : g == 1 ? Wxf_ : g == 2 ? Wxg_ : Wxo_);
    const float* src = (kc < 32) ? (Wh + (size_t)u * Hn + kc * 32 + klo)
                                 : (Wx + (size_t)u * En + (kc - 32) * 32 + klo);
    float4 v0 = ((const float4*)src)[0];
    float4 v1 = ((const float4*)src)[1];
    float w[8] = {v0.x, v0.y, v0.z, v0.w, v1.x, v1.y, v1.z, v1.w};
    #pragma unroll
    for (int j = 0; j < 8; ++j) {
        f16 hi = (f16)w[j];
        float lo = (w[j] - (float)hi) * 2048.0f;
        wpHi[(size_t)t * 8 + j] = hi;
        wpLo[(size_t)t * 8 + j] = (f16)lo;
    }
}

__global__ __launch_bounds__(256) void epack_kernel(
    const int* __restrict__ x, const float* __restrict__ emb,
    f16* __restrict__ eF)
{
    int t = blockIdx.x * 256 + threadIdx.x;   // 2097152 = 512*16*4*64
    int lane = t & 63;
    int q = t >> 6;
    int mt = q & 3; q >>= 2;
    int kc2 = q & 15;
    int s = q >> 4;
    int b = mt * 16 + (lane & 15);
    int tok = x[b * Sn + s];
    int k = kc2 * 32 + ((lane >> 4) << 3);
    const float* src = emb + (size_t)tok * En + k;
    float4 v0 = ((const float4*)src)[0];
    float4 v1 = ((const float4*)src)[1];
    f16* dst = eF + (size_t)t * 8;
    dst[0] = (f16)v0.x; dst[1] = (f16)v0.y; dst[2] = (f16)v0.z; dst[3] = (f16)v0.w;
    dst[4] = (f16)v1.x; dst[5] = (f16)v1.y; dst[6] = (f16)v1.z; dst[7] = (f16)v1.w;
}

// ---------------- fallback gx kernel (round-6 proven) ----------------
__global__ __launch_bounds__(256) void gx_chunk_kernel(
    const half8* __restrict__ eF,
    const half8* __restrict__ wpHi, const half8* __restrict__ wpLo,
    float* __restrict__ gx, int chunk)
{
    int lane = threadIdx.x & 63;
    int id = blockIdx.x * 4 + (threadIdx.x >> 6);
    int sc = id >> 8;            // 0..31
    int bb = id & 255;
    int s = chunk * RING + sc;

    const half8* eFs = eF + (size_t)s * 4096 + lane;
    const half8* bH = wpHi + ((size_t)(bb * 48 + 32)) * 64 + lane;
    const half8* bL = wpLo + ((size_t)(bb * 48 + 32)) * 64 + lane;

    f32x4 aH[4], aL[4];
    #pragma unroll
    for (int mt = 0; mt < 4; ++mt) { aH[mt] = (f32x4)0.0f; aL[mt] = (f32x4)0.0f; }

    for (int kcx = 0; kcx < 16; ++kcx) {
        half8 bh = bH[(size_t)kcx * 64];
        half8 bl = bL[(size_t)kcx * 64];
        #pragma unroll
        for (int mt = 0; mt < 4; ++mt) {
            half8 a = eFs[(size_t)((kcx * 4 + mt) * 64)];
            aH[mt] = __builtin_amdgcn_mfma_f32_16x16x32_f16(a, bh, aH[mt], 0, 0, 0);
            aL[mt] = __builtin_amdgcn_mfma_f32_16x16x32_f16(a, bl, aL[mt], 0, 0, 0);
        }
    }

    int n = lane & 15, g = n >> 2, du = n & 3;
    int col = (g << 10) + bb * 4 + du;
    float* g0 = gx + (size_t)sc * (Bn * 4096) + col;
    #pragma unroll
    for (int mt = 0; mt < 4; ++mt) {
        #pragma unroll
        for (int r = 0; r < 4; ++r) {
            int b = mt * 16 + ((lane >> 4) << 2) + r;
            g0[(size_t)b * 4096] = aH[mt][r] + aL[mt][r] * (1.0f / 2048.0f);
        }
    }
}

// ---------------- fallback per-step kernel (round-6 proven) ----------------
template<bool USE_GX>
__global__ __launch_bounds__(1024) void step_kernel(
    const f16* __restrict__ hFin, f16* __restrict__ hFout,
    const half8* __restrict__ eF,
    const half8* __restrict__ wpHi, const half8* __restrict__ wpLo,
    const float* __restrict__ gx,
    const float* __restrict__ bi, const float* __restrict__ bf,
    const float* __restrict__ bg, const float* __restrict__ bo,
    float* __restrict__ c, float* __restrict__ hFinal, int s)
{
    __shared__ float preW[16][256];       // 16 KB

    const int tid  = threadIdx.x;
    const int lane = tid & 63;
    const int wv   = tid >> 6;
    const int mt   = wv & 3;
    const int kq   = wv >> 2;
    const int bb   = blockIdx.x;

    const half8* hin = (const half8*)hFin + lane;
    const half8* bHb = wpHi + (size_t)(bb * 48) * 64 + lane;
    const half8* bLb = wpLo + (size_t)(bb * 48) * 64 + lane;

    f32x4 accH = {0.f, 0.f, 0.f, 0.f};
    f32x4 accL = {0.f, 0.f, 0.f, 0.f};

    if (USE_GX) {
        #pragma unroll
        for (int i = 0; i < 8; ++i) {
            int kc = kq * 8 + i;
            half8 a  = hin[(size_t)((kc * 4 + mt) * 64)];
            half8 bh = bHb[(size_t)kc * 64];
            half8 bl = bLb[(size_t)kc * 64];
            accH = __builtin_amdgcn_mfma_f32_16x16x32_f16(a, bh, accH, 0, 0, 0);
            accL = __builtin_amdgcn_mfma_f32_16x16x32_f16(a, bl, accL, 0, 0, 0);
        }
    } else {
        const half8* eFs = eF + (size_t)s * 4096 + lane;
        #pragma unroll
        for (int i = 0; i < 12; ++i) {
            int kc = kq * 12 + i;
            half8 a = (kc < 32) ? hin[(size_t)((kc * 4 + mt) * 64)]
                                : eFs[(size_t)(((kc - 32) * 4 + mt) * 64)];
            half8 bh = bHb[(size_t)kc * 64];
            half8 bl = bLb[(size_t)kc * 64];
            accH = __builtin_amdgcn_mfma_f32_16x16x32_f16(a, bh, accH, 0, 0, 0);
            accL = __builtin_amdgcn_mfma_f32_16x16x32_f16(a, bl, accL, 0, 0, 0);
        }
    }

    f32x4 v;
    #pragma unroll
    for (int r = 0; r < 4; ++r) v[r] = accH[r] + accL[r] * (1.0f / 2048.0f);
    *(f32x4*)&preW[wv][lane * 4] = v;
    __syncthreads();

    if (tid < 256) {
        const int bcell = tid >> 2, ducell = tid & 3;
        const int colcell = bb * 4 + ducell;          // h-unit 0..1023
        const int msub = bcell & 15, mtp = bcell >> 4;
        const int base_i = ((msub >> 2) * 16) * 4 + (msub & 3);
        float sg_[4];
        #pragma unroll
        for (int g = 0; g < 4; ++g) {
            int idx = base_i + (g * 4 + ducell) * 4;
            sg_[g] = preW[0 * 4 + mtp][idx] + preW[1 * 4 + mtp][idx]
                   + preW[2 * 4 + mtp][idx] + preW[3 * 4 + mtp][idx];
        }
        float si = sg_[0] + bi[colcell];
        float sf = sg_[1] + bf[colcell];
        float sg = sg_[2] + bg[colcell];
        float so = sg_[3] + bo[colcell];
        if (USE_GX) {
            const float* gr = gx + ((size_t)(s & (RING - 1)) * Bn + bcell) * 4096;
            si += gr[colcell];        sf += gr[1024 + colcell];
            sg += gr[2048 + colcell]; so += gr[3072 + colcell];
        }
        float it = 1.f / (1.f + expf(-si));
        float ft = 1.f / (1.f + expf(-sf));
        float gt = tanhf(sg);
        float ot = 1.f / (1.f + expf(-so));
        int gi = bcell * Hn + colcell;
        float cn = ft * c[gi] + it * gt;
        c[gi] = cn;
        float hn = ot * tanhf(cn);
        int kch = colcell >> 5, dk = colcell & 31;
        int lp  = ((dk >> 3) << 4) | (bcell & 15);
        int mtp2 = bcell >> 4;
        hFout[((size_t)((kch * 4 + mtp2) * 64 + lp)) * 8 + (dk & 7)] = (f16)hn;
        if (s == Sn - 1) hFinal[gi] = hn;
    }
}

// ---------------- per-chunk persistent cooperative kernel ----------------
// cnt layout (uint32 indices): arrival line j at j*32 (128 B apart, j=0..15).
// Block bb arrives on line (bb&15); each line gets 16 adds per barrier.
// Poll: wave 0 loads all 16 lines (lane&15), shfl_xor-sum, compare 256*(B+1).
__global__ __launch_bounds__(1024) void steps_chunk_coop(
    f16* __restrict__ hF,                 // 2 x 65536 f16 (double buffer)
    const half8* __restrict__ eF,
    const half8* __restrict__ wpHi, const half8* __restrict__ wpLo,
    float* __restrict__ gx,
    const float* __restrict__ bi, const float* __restrict__ bf,
    const float* __restrict__ bg, const float* __restrict__ bo,
    float* __restrict__ c, float* __restrict__ hFinal,
    unsigned* __restrict__ cntArr, int chunk)
{
    __shared__ alignas(16) f16 wHs[32 * 512];   // 32 KB  Wh hi, kc 0..31
    __shared__ alignas(16) f16 wLs[32 * 512];   // 32 KB  Wh lo
    __shared__ float preW[16][256];             // 16 KB

    const int tid  = threadIdx.x;
    const int lane = tid & 63;
    const int wv   = tid >> 6;
    const int mt   = wv & 3;
    const int kq   = wv >> 2;
    const int bb   = blockIdx.x;

    // ---- stage this block's Wh weights into LDS ----
    {
        const half8* srcH = wpHi + (size_t)(bb * 48) * 64;
        const half8* srcL = wpLo + (size_t)(bb * 48) * 64;
        half8* dH = (half8*)wHs;
        half8* dL = (half8*)wLs;
        #pragma unroll
        for (int i = 0; i < 2; ++i) {         // 2048 half8 per buffer
            dH[tid + i * 1024] = srcH[tid + i * 1024];
            dL[tid + i * 1024] = srcL[tid + i * 1024];
        }
    }

    // ---- gx prologue: wave wv computes sc = 2*wv, 2*wv+1 for this bb ----
    {
        const half8* bH = wpHi + ((size_t)(bb * 48 + 32)) * 64 + lane;
        const half8* bL = wpLo + ((size_t)(bb * 48 + 32)) * 64 + lane;
        #pragma unroll
        for (int t2 = 0; t2 < 2; ++t2) {
            int sc = wv * 2 + t2;
            int s = chunk * RING + sc;
            const half8* eFs = eF + (size_t)s * 4096 + lane;
            f32x4 aH[4], aL[4];
            #pragma unroll
            for (int m2 = 0; m2 < 4; ++m2) { aH[m2] = (f32x4)0.0f; aL[m2] = (f32x4)0.0f; }
            for (int kcx = 0; kcx < 16; ++kcx) {
                half8 bh = bH[(size_t)kcx * 64];
                half8 bl = bL[(size_t)kcx * 64];
                #pragma unroll
                for (int m2 = 0; m2 < 4; ++m2) {
                    half8 a = eFs[(size_t)((kcx * 4 + m2) * 64)];
                    aH[m2] = __builtin_amdgcn_mfma_f32_16x16x32_f16(a, bh, aH[m2], 0, 0, 0);
                    aL[m2] = __builtin_amdgcn_mfma_f32_16x16x32_f16(a, bl, aL[m2], 0, 0, 0);
                }
            }
            int n = lane & 15, g = n >> 2, du = n & 3;
            int col = (g << 10) + bb * 4 + du;
            float* g0 = gx + (size_t)sc * (Bn * 4096) + col;
            #pragma unroll
            for (int m2 = 0; m2 < 4; ++m2) {
                #pragma unroll
                for (int r = 0; r < 4; ++r) {
                    int b = m2 * 16 + ((lane >> 4) << 2) + r;
                    g0[(size_t)b * 4096] = aH[m2][r] + aL[m2][r] * (1.0f / 2048.0f);
                }
            }
        }
    }

    // ---- per-cell persistent state ----
    float creg = 0.f, bi_r = 0.f, bf_r = 0.f, bg_r = 0.f, bo_r = 0.f;
    int bcell = 0, ducell = 0, colcell = 0, gi = 0, mtp = 0, base_i = 0;
    int kch = 0, dk = 0, lp = 0;
    if (tid < 256) {
        bcell = tid >> 2; ducell = tid & 3;
        colcell = bb * 4 + ducell;
        gi = bcell * Hn + colcell;
        int msub = bcell & 15; mtp = bcell >> 4;
        base_i = ((msub >> 2) * 16) * 4 + (msub & 3);
        creg = c[gi];
        bi_r = bi[colcell]; bf_r = bf[colcell];
        bg_r = bg[colcell]; bo_r = bo[colcell];
        kch = colcell >> 5; dk = colcell & 31;
        lp  = ((dk >> 3) << 4) | (bcell & 15);
    }

    __syncthreads();   // gx prologue + LDS staging complete

    const half8* wHl = (const half8*)wHs + lane;
    const half8* wLl = (const half8*)wLs + lane;

    // gx for step 0 (prefetched; later steps prefetched under the barrier)
    float gxi = 0.f, gxf = 0.f, gxg = 0.f, gxo = 0.f;
    if (tid < 256) {
        const float* gr = gx + ((size_t)0 * Bn + bcell) * 4096 + colcell;
        gxi = gr[0];    gxf = gr[1024];
        gxg = gr[2048]; gxo = gr[3072];
    }

    #pragma unroll 1
    for (int sc = 0; sc < RING; ++sc) {
        const int s = chunk * RING + sc;
        const f16* hbase = hF + (size_t)(s & 1) * 65536;
        f16* hout = hF + (size_t)((s + 1) & 1) * 65536;

        // hF fragment loads: device-scope relaxed atomics (bypass stale
        // L1/L2, served from MALL where other blocks' stores landed)
        half8 afr[8];
        #pragma unroll
        for (int i = 0; i < 8; ++i) {
            const int kc = kq * 8 + i;
            const u64* p = (const u64*)(hbase
                + ((size_t)((kc * 4 + mt) * 64 + lane)) * 8);
            u64x2 u;
            u.x = __hip_atomic_load(p, __ATOMIC_RELAXED,
                                    __HIP_MEMORY_SCOPE_AGENT);
            u.y = __hip_atomic_load(p + 1, __ATOMIC_RELAXED,
                                    __HIP_MEMORY_SCOPE_AGENT);
            afr[i] = __builtin_bit_cast(half8, u);
        }

        f32x4 accH = {0.f, 0.f, 0.f, 0.f};
        f32x4 accL = {0.f, 0.f, 0.f, 0.f};
        #pragma unroll
        for (int i = 0; i < 8; ++i) {
            const int kc = kq * 8 + i;
            half8 bh = wHl[(size_t)kc * 64];
            half8 bl = wLl[(size_t)kc * 64];
            accH = __builtin_amdgcn_mfma_f32_16x16x32_f16(afr[i], bh, accH, 0, 0, 0);
            accL = __builtin_amdgcn_mfma_f32_16x16x32_f16(afr[i], bl, accL, 0, 0, 0);
        }
        f32x4 v;
        #pragma unroll
        for (int r = 0; r < 4; ++r) v[r] = accH[r] + accL[r] * (1.0f / 2048.0f);
        *(f32x4*)&preW[wv][lane * 4] = v;
        __syncthreads();

        if (tid < 256) {
            float sg_[4];
            #pragma unroll
            for (int g = 0; g < 4; ++g) {
                int idx = base_i + (g * 4 + ducell) * 4;
                sg_[g] = preW[mtp][idx] + preW[4 + mtp][idx]
                       + preW[8 + mtp][idx] + preW[12 + mtp][idx];
            }
            float si = sg_[0] + bi_r + gxi;
            float sf = sg_[1] + bf_r + gxf;
            float sg = sg_[2] + bg_r + gxg;
            float so = sg_[3] + bo_r + gxo;
            float it = 1.f / (1.f + expf(-si));
            float ft = 1.f / (1.f + expf(-sf));
            float gt = tanhf(sg);
            float ot = 1.f / (1.f + expf(-so));
            float cn = ft * creg + it * gt;
            creg = cn;
            float hn = ot * tanhf(cn);
            // pack 4 f16 (ducell 0..3 = 4 adjacent lanes) -> one 8 B store
            union { f16 h; unsigned short u; } cv;
            cv.h = (f16)hn;
            unsigned v0 = cv.u;
            unsigned v1 = (unsigned)__shfl_down((int)v0, 1, 64);
            unsigned v2 = (unsigned)__shfl_down((int)v0, 2, 64);
            unsigned v3 = (unsigned)__shfl_down((int)v0, 3, 64);
            if (ducell == 0) {
                u64 pack = (u64)(v0 & 0xffffu) | ((u64)(v1 & 0xffffu) << 16)
                         | ((u64)(v2 & 0xffffu) << 32) | ((u64)(v3 & 0xffffu) << 48);
                u64* paddr = (u64*)(hout
                    + ((size_t)((kch * 4 + mtp) * 64 + lp)) * 8 + (dk & 7));
                __hip_atomic_store(paddr, pack, __ATOMIC_RELAXED,
                                   __HIP_MEMORY_SCOPE_AGENT);
            }
            if (s == Sn - 1) hFinal[gi] = hn;
        }

        // ---- flat barrier (skip on last step of chunk) ----
        if (sc < RING - 1) {
            asm volatile("s_waitcnt vmcnt(0)" ::: "memory");  // drain stores
            __syncthreads();
            if (tid == 0)
                __hip_atomic_fetch_add(cntArr + (((unsigned)bb & 15u) << 5), 1u,
                                       __ATOMIC_RELAXED, __HIP_MEMORY_SCOPE_AGENT);
            // prefetch next step's gx under the barrier wait
            if (tid < 256) {
                const float* gr = gx + ((size_t)(sc + 1) * Bn + bcell) * 4096
                                + colcell;
                gxi = gr[0];    gxf = gr[1024];
                gxg = gr[2048]; gxo = gr[3072];
            }
            if (wv == 0) {
                const unsigned B = (unsigned)(chunk * (RING - 1) + sc);
                const unsigned need = 256u * (B + 1u);
                while (true) {
                    unsigned pv = __hip_atomic_load(
                        cntArr + (((unsigned)lane & 15u) << 5),
                        __ATOMIC_RELAXED, __HIP_MEMORY_SCOPE_AGENT);
                    pv += (unsigned)__shfl_xor((int)pv, 1, 64);
                    pv += (unsigned)__shfl_xor((int)pv, 2, 64);
                    pv += (unsigned)__shfl_xor((int)pv, 4, 64);
                    pv += (unsigned)__shfl_xor((int)pv, 8, 64);
                    if (pv >= need) break;
                    __builtin_amdgcn_s_sleep(1);
                }
            }
            __syncthreads();
        }
    }

    if (tid < 256) c[gi] = creg;
}

// ---- tail ----
__global__ __launch_bounds__(256) void copy_hc(
    const float* __restrict__ h, const float* __restrict__ c,
    float* __restrict__ out)
{
    int i = blockIdx.x * 256 + threadIdx.x;
    out[128 + i] = h[i];
    out[128 + Bn * Hn + i] = c[i];
}

__global__ __launch_bounds__(64) void classifier(
    const float* __restrict__ h, const float* __restrict__ Vw,
    const float* __restrict__ Vb, float* __restrict__ out)
{
    int bid = blockIdx.x;
    int b = bid >> 1, n = bid & 1;
    int lane = threadIdx.x;
    float sum = 0.f;
    for (int k = lane; k < Hn; k += 64)
        sum += h[b * Hn + k] * Vw[n * Hn + k];
    #pragma unroll
    for (int off = 32; off > 0; off >>= 1)
        sum += __shfl_down(sum, off, 64);
    if (lane == 0)
        out[b * 2 + n] = sum + Vb[n];
}

// ======================= fallback (round-1 proven path) =======================

#define KT 128
#define KTP 132

__global__ __launch_bounds__(256) void lstm_step_fb(
    const int* __restrict__ x, const float* __restrict__ emb,
    const float* __restrict__ Wxi, const float* __restrict__ Wxf,
    const float* __restrict__ Wxg, const float* __restrict__ Wxo,
    const float* __restrict__ bi, const float* __restrict__ bf,
    const float* __restrict__ bg, const float* __restrict__ bo,
    const float* __restrict__ Whi, const float* __restrict__ Whf,
    const float* __restrict__ Whg, const float* __restrict__ Who,
    const float* __restrict__ h_in, const float* __restrict__ c_in,
    float* __restrict__ h_out, float* __restrict__ c_out, int s)
{
    __shared__ float sh[Bn][KTP];
    __shared__ float sw[16][KTP];
    const int tid = threadIdx.x;
    const int b = tid >> 2, j = tid & 3;
    const int cb = blockIdx.x * 4, col = cb + j;
    float acc0 = 0.f, acc1 = 0.f, acc2 = 0.f, acc3 = 0.f;

    for (int k0 = 0; k0 < En; k0 += KT) {
        for (int i = tid; i < Bn * (KT / 4); i += 256) {
            int bl = i >> 5, k4 = (i & 31) << 2;
            int tok = x[bl * Sn + s];
            *reinterpret_cast<float4*>(&sh[bl][k4]) =
                *reinterpret_cast<const float4*>(&emb[(size_t)tok * En + k0 + k4]);
        }
        for (int i = tid; i < 16 * (KT / 4); i += 256) {
            int r = i >> 5, k4 = (i & 31) << 2;
            const float* Wg = (r < 8) ? ((r < 4) ? Wxi : Wxf)
                                      : ((r < 12) ? Wxg : Wxo);
            *reinterpret_cast<float4*>(&sw[r][k4]) =
                *reinterpret_cast<const float4*>(&Wg[(size_t)(cb + (r & 3)) * En + k0 + k4]);
        }
        __syncthreads();
        #pragma unroll 8
        for (int k = 0; k < KT; k += 4) {
            float4 hv = *reinterpret_cast<const float4*>(&sh[b][k]);
            float4 w0 = *reinterpret_cast<const float4*>(&sw[j][k]);
            float4 w1 = *reinterpret_cast<const float4*>(&sw[4 + j][k]);
            float4 w2 = *reinterpret_cast<const float4*>(&sw[8 + j][k]);
            float4 w3 = *reinterpret_cast<const float4*>(&sw[12 + j][k]);
            acc0 += hv.x*w0.x + hv.y*w0.y + hv.z*w0.z + hv.w*w0.w;
            acc1 += hv.x*w1.x + hv.y*w1.y + hv.z*w1.z + hv.w*w1.w;
            acc2 += hv.x*w2.x + hv.y*w2.y + hv.z*w2.z + hv.w*w2.w;
            acc3 += hv.x*w3.x + hv.y*w3.y + hv.z*w3.z + hv.w*w3.w;
        }
        __syncthreads();
    }
    for (int k0 = 0; k0 < Hn; k0 += KT) {
        for (int i = tid; i < Bn * (KT / 4); i += 256) {
            int bl = i >> 5, k4 = (i & 31) << 2;
            *reinterpret_cast<float4*>(&sh[bl][k4]) =
                *reinterpret_cast<const float4*>(&h_in[(size_t)bl * Hn + k0 + k4]);
        }
        for (int i = tid; i < 16 * (KT / 4); i += 256) {
            int r = i >> 5, k4 = (i & 31) << 2;
            const float* Wg = (r < 8) ? ((r < 4) ? Whi : Whf)
                                      : ((r < 12) ? Whg : Who);
            *reinterpret_cast<float4*>(&sw[r][k4]) =
                *reinterpret_cast<const float4*>(&Wg[(size_t)(cb + (r & 3)) * Hn + k0 + k4]);
        }
        __syncthreads();
        #pragma unroll 8
        for (int k = 0; k < KT; k += 4) {
            float4 hv = *reinterpret_cast<const float4*>(&sh[b][k]);
            float4 w0 = *reinterpret_cast<const float4*>(&sw[j][k]);
            float4 w1 = *reinterpret_cast<const float4*>(&sw[4 + j][k]);
            float4 w2 = *reinterpret_cast<const float4*>(&sw[8 + j][k]);
            float4 w3 = *reinterpret_cast<const float4*>(&sw[12 + j][k]);
            acc0 += hv.x*w0.x + hv.y*w0.y + hv.z*w0.z + hv.w*w0.w;
            acc1 += hv.x*w1.x + hv.y*w1.y + hv.z*w1.z + hv.w*w1.w;
            acc2 += hv.x*w2.x + hv.y*w2.y + hv.z*w2.z + hv.w*w2.w;
            acc3 += hv.x*w3.x + hv.y*w3.y + hv.z*w3.z + hv.w*w3.w;
        }
        __syncthreads();
    }
    acc0 += bi[col]; acc1 += bf[col]; acc2 += bg[col]; acc3 += bo[col];
    float it = 1.f / (1.f + expf(-acc0));
    float ft = 1.f / (1.f + expf(-acc1));
    float gt = tanhf(acc2);
    float ot = 1.f / (1.f + expf(-acc3));
    float cn = ft * c_in[b * Hn + col] + it * gt;
    c_out[b * Hn + col] = cn;
    h_out[b * Hn + col] = ot * tanhf(cn);
}

// ======================= launcher =======================

extern "C" void kernel_launch(void* const* d_in, const int* in_sizes, int n_in,
                              void* d_out, int out_size, void* d_ws, size_t ws_size,
                              hipStream_t stream) {
    const int*   x   = (const int*)  d_in[0];
    const float* emb = (const float*)d_in[1];
    const float* Wxi = (const float*)d_in[2];
    const float* bi  = (const float*)d_in[3];
    const float* Whi = (const float*)d_in[4];
    const float* Wxf = (const float*)d_in[5];
    const float* bf  = (const float*)d_in[6];
    const float* Whf = (const float*)d_in[7];
    const float* Wxg = (const float*)d_in[8];
    const float* bg  = (const float*)d_in[9];
    const float* Whg = (const float*)d_in[10];
    const float* Wxo = (const float*)d_in[11];
    const float* bo  = (const float*)d_in[12];
    const float* Who = (const float*)d_in[13];
    const float* Vw  = (const float*)d_in[14];
    const float* Vb  = (const float*)d_in[15];
    float* out = (float*)d_out;

    // ws: [hF 256K][c 256K][h 256K][eF 32M][wpHi 12M][wpLo 12M][gx 32M][cnt 4K]
    const size_t szHF = (size_t)2 * 65536 * sizeof(f16);              // 256 KB
    const size_t szC  = (size_t)Bn * Hn * sizeof(float);              // 256 KB
    const size_t szEF = (size_t)Sn * 16 * 4 * 64 * 8 * sizeof(f16);   // 32 MB
    const size_t szWp = (size_t)256 * 48 * 64 * 8 * sizeof(f16);      // 12 MB
    const size_t szGx = (size_t)RING * Bn * 4096 * sizeof(float);     // 32 MB
    const size_t need_mid  = szHF + 2 * szC + szEF + 2 * szWp;
    const size_t need_gx   = need_mid + szGx;
    const size_t need_coop = need_gx + 4096;

    if (ws_size >= need_mid) {
        const bool haveGx   = (ws_size >= need_gx);
        const bool haveCoop = (ws_size >= need_coop);
        char* base = (char*)d_ws;
        f16*   hF   = (f16*)base;   base += szHF;
        float* c    = (float*)base; base += szC;
        float* h    = (float*)base; base += szC;
        f16*   eF   = (f16*)base;   base += szEF;
        f16*   wpHi = (f16*)base;   base += szWp;
        f16*   wpLo = (f16*)base;   base += szWp;
        float* gx   = (float*)base; base += szGx;
        unsigned* cnt = (unsigned*)base;

        hipMemsetAsync(d_ws, 0, szHF + szC, stream);   // hF both bufs + c
        if (haveCoop) hipMemsetAsync(cnt, 0, 4096, stream);  // arrival lines
        wpack_kernel<<<dim3(3072), dim3(256), 0, stream>>>(
            Whi, Whf, Whg, Who, Wxi, Wxf, Wxg, Wxo, wpHi, wpLo);
        epack_kernel<<<dim3(8192), dim3(256), 0, stream>>>(x, emb, eF);

        if (haveGx) {
            bool coop = haveCoop;
            for (int chunk = 0; chunk < Sn / RING; ++chunk) {
                if (coop) {
                    f16* hFp = hF;
                    const half8* eF8   = (const half8*)eF;
                    const half8* wpHi8 = (const half8*)wpHi;
                    const half8* wpLo8 = (const half8*)wpLo;
                    float* gxp = gx;
                    const float* bip = bi; const float* bfp = bf;
                    const float* bgp = bg; const float* bop = bo;
                    float* cp = c; float* hp = h;
                    unsigned* cntp = cnt;
                    int ci = chunk;
                    void* args[] = { &hFp, &eF8, &wpHi8, &wpLo8, &gxp,
                                     &bip, &bfp, &bgp, &bop, &cp, &hp,
                                     &cntp, &ci };
                    hipError_t e = hipLaunchCooperativeKernel(
                        (const void*)steps_chunk_coop, dim3(NBLK), dim3(1024),
                        args, 0, stream);
                    if (e != hipSuccess) { coop = false; (void)hipGetLastError(); }
                }
                if (!coop) {
                    gx_chunk_kernel<<<dim3(2048), dim3(256), 0, stream>>>(
                        (const half8*)eF, (const half8*)wpHi, (const half8*)wpLo,
                        gx, chunk);
                    for (int sc = 0; sc < RING; ++sc) {
                        int s = chunk * RING + sc;
                        const f16* hin  = hF + (size_t)(s & 1) * 65536;
                        f16*       hout = hF + (size_t)((s + 1) & 1) * 65536;
                        step_kernel<true><<<dim3(256), dim3(1024), 0, stream>>>(
                            hin, hout, (const half8*)eF,
                            (const half8*)wpHi, (const half8*)wpLo,
                            gx, bi, bf, bg, bo, c, h, s);
                    }
                }
            }
        } else {
            for (int s = 0; s < Sn; ++s) {
                const f16* hin  = hF + (size_t)(s & 1) * 65536;
                f16*       hout = hF + (size_t)((s + 1) & 1) * 65536;
                step_kernel<false><<<dim3(256), dim3(1024), 0, stream>>>(
                    hin, hout, (const half8*)eF,
                    (const half8*)wpHi, (const half8*)wpLo,
                    (const float*)nullptr, bi, bf, bg, bo, c, h, s);
            }
        }
        copy_hc<<<dim3(Bn * Hn / 256), dim3(256), 0, stream>>>(h, c, out);
        classifier<<<dim3(Bn * 2), dim3(64), 0, stream>>>(h, Vw, Vb, out);
    } else {
        float* hA = (float*)d_ws;
        float* cA = hA + Bn * Hn;
        float* hB = cA + Bn * Hn;
        float* cB = hB + Bn * Hn;
        hipMemsetAsync(d_ws, 0, (size_t)2 * Bn * Hn * sizeof(float), stream);
        for (int s = 0; s < Sn; ++s) {
            const float* hi = (s & 1) ? hB : hA;
            const float* ci = (s & 1) ? cB : cA;
            float* ho = (s & 1) ? hA : hB;
            float* co = (s & 1) ? cA : cB;
            lstm_step_fb<<<dim3(Hn / 4), dim3(256), 0, stream>>>(
                x, emb, Wxi, Wxf, Wxg, Wxo, bi, bf, bg, bo,
                Whi, Whf, Whg, Who, hi, ci, ho, co, s);
        }
        copy_hc<<<dim3(Bn * Hn / 256), dim3(256), 0, stream>>>(hA, cA, out);
        classifier<<<dim3(Bn * 2), dim3(64), 0, stream>>>(hA, Vw, Vb, out);
    }
}

// Round 7
// 3759.601 us; speedup vs baseline: 1.4218x; 1.1320x over previous
//
#include <hip/hip_runtime.h>
#include <math.h>

#define Bn 64
#define Hn 1024
#define En 512
#define Sn 512
#define RING 32
#define NBLK 256

typedef _Float16 f16;
typedef _Float16 half8 __attribute__((ext_vector_type(8)));
typedef float f32x4 __attribute__((ext_vector_type(4)));
typedef unsigned long long u64;
typedef u64 u64x2 __attribute__((ext_vector_type(2)));

// ============================================================================
// Round 13: round-12 kernel (best: 241 us/chunk, 4255 total) + per-step h RING.
//   The sc1-bypass hF loads existed because double-buffer addresses recycle
//   every 2 steps (stale XCD L2 lines). Cost: every block pulls 128 KB from
//   MALL each step (32 MB/step broadcast, ~2.5 us + 900ns latency).
//   Fix: ring of 513 x 128 KB h buffers - every step writes a FRESH address,
//   so no L2 line can ever be stale, and hF reads become PLAIN loads:
//     - first reader per XCD misses -> fills local L2 (same-line misses
//       merge in MSHRs: 128 KB crosses fabric once per XCD, not 32x)
//     - other 31 blocks hit local L2 (~200cyc) -> load stage ~1 us
//   Stores remain __hip_atomic_store AGENT (write-through to MALL, no local
//   allocate on CDNA -> no producer-side stale lines; all writers land at
//   MALL before the barrier, readers' L2 fills fetch the merged line).
//   Falls back to the round-12 double-buffer coop kernel if ws too small.
// Everything else identical to round 12:
//   - flat 16-line barrier, wave-0 poll, gx prefetch, packed 8 B h stores
//   - gx block-local, plain loads/stores; Wh in LDS; c in registers
// ============================================================================

__global__ __launch_bounds__(256) void wpack_kernel(
    const float* __restrict__ Whi_, const float* __restrict__ Whf_,
    const float* __restrict__ Whg_, const float* __restrict__ Who_,
    const float* __restrict__ Wxi_, const float* __restrict__ Wxf_,
    const float* __restrict__ Wxg_, const float* __restrict__ Wxo_,
    f16* __restrict__ wpHi, f16* __restrict__ wpLo)
{
    int t = blockIdx.x * 256 + threadIdx.x;   // 786432 = 256*48*64
    int lane = t & 63;
    int rest = t >> 6;
    int kc = rest % 48;
    int bb = rest / 48;
    int n = lane & 15, g = n >> 2, du = n & 3;
    int u = bb * 4 + du;
    int klo = (lane >> 4) << 3;
    const float* Wh = (g == 0 ? Whi_ : g == 1 ? Whf_ : g == 2 ? Whg_ : Who_);
    const float* Wx = (g == 0 ? Wxi_ : g == 1 ? Wxf_ : g == 2 ? Wxg_ : Wxo_);
    const float* src = (kc < 32) ? (Wh + (size_t)u * Hn + kc * 32 + klo)
                                 : (Wx + (size_t)u * En + (kc - 32) * 32 + klo);
    float4 v0 = ((const float4*)src)[0];
    float4 v1 = ((const float4*)src)[1];
    float w[8] = {v0.x, v0.y, v0.z, v0.w, v1.x, v1.y, v1.z, v1.w};
    #pragma unroll
    for (int j = 0; j < 8; ++j) {
        f16 hi = (f16)w[j];
        float lo = (w[j] - (float)hi) * 2048.0f;
        wpHi[(size_t)t * 8 + j] = hi;
        wpLo[(size_t)t * 8 + j] = (f16)lo;
    }
}

__global__ __launch_bounds__(256) void epack_kernel(
    const int* __restrict__ x, const float* __restrict__ emb,
    f16* __restrict__ eF)
{
    int t = blockIdx.x * 256 + threadIdx.x;   // 2097152 = 512*16*4*64
    int lane = t & 63;
    int q = t >> 6;
    int mt = q & 3; q >>= 2;
    int kc2 = q & 15;
    int s = q >> 4;
    int b = mt * 16 + (lane & 15);
    int tok = x[b * Sn + s];
    int k = kc2 * 32 + ((lane >> 4) << 3);
    const float* src = emb + (size_t)tok * En + k;
    float4 v0 = ((const float4*)src)[0];
    float4 v1 = ((const float4*)src)[1];
    f16* dst = eF + (size_t)t * 8;
    dst[0] = (f16)v0.x; dst[1] = (f16)v0.y; dst[2] = (f16)v0.z; dst[3] = (f16)v0.w;
    dst[4] = (f16)v1.x; dst[5] = (f16)v1.y; dst[6] = (f16)v1.z; dst[7] = (f16)v1.w;
}

// ---------------- fallback gx kernel (round-6 proven) ----------------
__global__ __launch_bounds__(256) void gx_chunk_kernel(
    const half8* __restrict__ eF,
    const half8* __restrict__ wpHi, const half8* __restrict__ wpLo,
    float* __restrict__ gx, int chunk)
{
    int lane = threadIdx.x & 63;
    int id = blockIdx.x * 4 + (threadIdx.x >> 6);
    int sc = id >> 8;            // 0..31
    int bb = id & 255;
    int s = chunk * RING + sc;

    const half8* eFs = eF + (size_t)s * 4096 + lane;
    const half8* bH = wpHi + ((size_t)(bb * 48 + 32)) * 64 + lane;
    const half8* bL = wpLo + ((size_t)(bb * 48 + 32)) * 64 + lane;

    f32x4 aH[4], aL[4];
    #pragma unroll
    for (int mt = 0; mt < 4; ++mt) { aH[mt] = (f32x4)0.0f; aL[mt] = (f32x4)0.0f; }

    for (int kcx = 0; kcx < 16; ++kcx) {
        half8 bh = bH[(size_t)kcx * 64];
        half8 bl = bL[(size_t)kcx * 64];
        #pragma unroll
        for (int mt = 0; mt < 4; ++mt) {
            half8 a = eFs[(size_t)((kcx * 4 + mt) * 64)];
            aH[mt] = __builtin_amdgcn_mfma_f32_16x16x32_f16(a, bh, aH[mt], 0, 0, 0);
            aL[mt] = __builtin_amdgcn_mfma_f32_16x16x32_f16(a, bl, aL[mt], 0, 0, 0);
        }
    }

    int n = lane & 15, g = n >> 2, du = n & 3;
    int col = (g << 10) + bb * 4 + du;
    float* g0 = gx + (size_t)sc * (Bn * 4096) + col;
    #pragma unroll
    for (int mt = 0; mt < 4; ++mt) {
        #pragma unroll
        for (int r = 0; r < 4; ++r) {
            int b = mt * 16 + ((lane >> 4) << 2) + r;
            g0[(size_t)b * 4096] = aH[mt][r] + aL[mt][r] * (1.0f / 2048.0f);
        }
    }
}

// ---------------- fallback per-step kernel (round-6 proven) ----------------
template<bool USE_GX>
__global__ __launch_bounds__(1024) void step_kernel(
    const f16* __restrict__ hFin, f16* __restrict__ hFout,
    const half8* __restrict__ eF,
    const half8* __restrict__ wpHi, const half8* __restrict__ wpLo,
    const float* __restrict__ gx,
    const float* __restrict__ bi, const float* __restrict__ bf,
    const float* __restrict__ bg, const float* __restrict__ bo,
    float* __restrict__ c, float* __restrict__ hFinal, int s)
{
    __shared__ float preW[16][256];       // 16 KB

    const int tid  = threadIdx.x;
    const int lane = tid & 63;
    const int wv   = tid >> 6;
    const int mt   = wv & 3;
    const int kq   = wv >> 2;
    const int bb   = blockIdx.x;

    const half8* hin = (const half8*)hFin + lane;
    const half8* bHb = wpHi + (size_t)(bb * 48) * 64 + lane;
    const half8* bLb = wpLo + (size_t)(bb * 48) * 64 + lane;

    f32x4 accH = {0.f, 0.f, 0.f, 0.f};
    f32x4 accL = {0.f, 0.f, 0.f, 0.f};

    if (USE_GX) {
        #pragma unroll
        for (int i = 0; i < 8; ++i) {
            int kc = kq * 8 + i;
            half8 a  = hin[(size_t)((kc * 4 + mt) * 64)];
            half8 bh = bHb[(size_t)kc * 64];
            half8 bl = bLb[(size_t)kc * 64];
            accH = __builtin_amdgcn_mfma_f32_16x16x32_f16(a, bh, accH, 0, 0, 0);
            accL = __builtin_amdgcn_mfma_f32_16x16x32_f16(a, bl, accL, 0, 0, 0);
        }
    } else {
        const half8* eFs = eF + (size_t)s * 4096 + lane;
        #pragma unroll
        for (int i = 0; i < 12; ++i) {
            int kc = kq * 12 + i;
            half8 a = (kc < 32) ? hin[(size_t)((kc * 4 + mt) * 64)]
                                : eFs[(size_t)(((kc - 32) * 4 + mt) * 64)];
            half8 bh = bHb[(size_t)kc * 64];
            half8 bl = bLb[(size_t)kc * 64];
            accH = __builtin_amdgcn_mfma_f32_16x16x32_f16(a, bh, accH, 0, 0, 0);
            accL = __builtin_amdgcn_mfma_f32_16x16x32_f16(a, bl, accL, 0, 0, 0);
        }
    }

    f32x4 v;
    #pragma unroll
    for (int r = 0; r < 4; ++r) v[r] = accH[r] + accL[r] * (1.0f / 2048.0f);
    *(f32x4*)&preW[wv][lane * 4] = v;
    __syncthreads();

    if (tid < 256) {
        const int bcell = tid >> 2, ducell = tid & 3;
        const int colcell = bb * 4 + ducell;          // h-unit 0..1023
        const int msub = bcell & 15, mtp = bcell >> 4;
        const int base_i = ((msub >> 2) * 16) * 4 + (msub & 3);
        float sg_[4];
        #pragma unroll
        for (int g = 0; g < 4; ++g) {
            int idx = base_i + (g * 4 + ducell) * 4;
            sg_[g] = preW[0 * 4 + mtp][idx] + preW[1 * 4 + mtp][idx]
                   + preW[2 * 4 + mtp][idx] + preW[3 * 4 + mtp][idx];
        }
        float si = sg_[0] + bi[colcell];
        float sf = sg_[1] + bf[colcell];
        float sg = sg_[2] + bg[colcell];
        float so = sg_[3] + bo[colcell];
        if (USE_GX) {
            const float* gr = gx + ((size_t)(s & (RING - 1)) * Bn + bcell) * 4096;
            si += gr[colcell];        sf += gr[1024 + colcell];
            sg += gr[2048 + colcell]; so += gr[3072 + colcell];
        }
        float it = 1.f / (1.f + expf(-si));
        float ft = 1.f / (1.f + expf(-sf));
        float gt = tanhf(sg);
        float ot = 1.f / (1.f + expf(-so));
        int gi = bcell * Hn + colcell;
        float cn = ft * c[gi] + it * gt;
        c[gi] = cn;
        float hn = ot * tanhf(cn);
        int kch = colcell >> 5, dk = colcell & 31;
        int lp  = ((dk >> 3) << 4) | (bcell & 15);
        int mtp2 = bcell >> 4;
        hFout[((size_t)((kch * 4 + mtp2) * 64 + lp)) * 8 + (dk & 7)] = (f16)hn;
        if (s == Sn - 1) hFinal[gi] = hn;
    }
}

// ---------------- per-chunk persistent cooperative kernel ----------------
// cnt layout (uint32 indices): arrival line j at j*32 (128 B apart, j=0..15).
// Block bb arrives on line (bb&15); each line gets 16 adds per barrier.
// Poll: wave 0 loads all 16 lines (lane&15), shfl_xor-sum, compare 256*(B+1).
// RINGM: h buffers hRing[s] (fresh address per step, plain loads, L2-shared).
template<bool RINGM>
__global__ __launch_bounds__(1024) void steps_chunk_coop(
    f16* __restrict__ hF,                 // 2 x 65536 f16 (double buffer)
    f16* __restrict__ hRing,              // 513 x 65536 f16 (RINGM only)
    const half8* __restrict__ eF,
    const half8* __restrict__ wpHi, const half8* __restrict__ wpLo,
    float* __restrict__ gx,
    const float* __restrict__ bi, const float* __restrict__ bf,
    const float* __restrict__ bg, const float* __restrict__ bo,
    float* __restrict__ c, float* __restrict__ hFinal,
    unsigned* __restrict__ cntArr, int chunk)
{
    __shared__ alignas(16) f16 wHs[32 * 512];   // 32 KB  Wh hi, kc 0..31
    __shared__ alignas(16) f16 wLs[32 * 512];   // 32 KB  Wh lo
    __shared__ float preW[16][256];             // 16 KB

    const int tid  = threadIdx.x;
    const int lane = tid & 63;
    const int wv   = tid >> 6;
    const int mt   = wv & 3;
    const int kq   = wv >> 2;
    const int bb   = blockIdx.x;

    // ---- stage this block's Wh weights into LDS ----
    {
        const half8* srcH = wpHi + (size_t)(bb * 48) * 64;
        const half8* srcL = wpLo + (size_t)(bb * 48) * 64;
        half8* dH = (half8*)wHs;
        half8* dL = (half8*)wLs;
        #pragma unroll
        for (int i = 0; i < 2; ++i) {         // 2048 half8 per buffer
            dH[tid + i * 1024] = srcH[tid + i * 1024];
            dL[tid + i * 1024] = srcL[tid + i * 1024];
        }
    }

    // ---- gx prologue: wave wv computes sc = 2*wv, 2*wv+1 for this bb ----
    {
        const half8* bH = wpHi + ((size_t)(bb * 48 + 32)) * 64 + lane;
        const half8* bL = wpLo + ((size_t)(bb * 48 + 32)) * 64 + lane;
        #pragma unroll
        for (int t2 = 0; t2 < 2; ++t2) {
            int sc = wv * 2 + t2;
            int s = chunk * RING + sc;
            const half8* eFs = eF + (size_t)s * 4096 + lane;
            f32x4 aH[4], aL[4];
            #pragma unroll
            for (int m2 = 0; m2 < 4; ++m2) { aH[m2] = (f32x4)0.0f; aL[m2] = (f32x4)0.0f; }
            for (int kcx = 0; kcx < 16; ++kcx) {
                half8 bh = bH[(size_t)kcx * 64];
                half8 bl = bL[(size_t)kcx * 64];
                #pragma unroll
                for (int m2 = 0; m2 < 4; ++m2) {
                    half8 a = eFs[(size_t)((kcx * 4 + m2) * 64)];
                    aH[m2] = __builtin_amdgcn_mfma_f32_16x16x32_f16(a, bh, aH[m2], 0, 0, 0);
                    aL[m2] = __builtin_amdgcn_mfma_f32_16x16x32_f16(a, bl, aL[m2], 0, 0, 0);
                }
            }
            int n = lane & 15, g = n >> 2, du = n & 3;
            int col = (g << 10) + bb * 4 + du;
            float* g0 = gx + (size_t)sc * (Bn * 4096) + col;
            #pragma unroll
            for (int m2 = 0; m2 < 4; ++m2) {
                #pragma unroll
                for (int r = 0; r < 4; ++r) {
                    int b = m2 * 16 + ((lane >> 4) << 2) + r;
                    g0[(size_t)b * 4096] = aH[m2][r] + aL[m2][r] * (1.0f / 2048.0f);
                }
            }
        }
    }

    // ---- per-cell persistent state ----
    float creg = 0.f, bi_r = 0.f, bf_r = 0.f, bg_r = 0.f, bo_r = 0.f;
    int bcell = 0, ducell = 0, colcell = 0, gi = 0, mtp = 0, base_i = 0;
    int kch = 0, dk = 0, lp = 0;
    if (tid < 256) {
        bcell = tid >> 2; ducell = tid & 3;
        colcell = bb * 4 + ducell;
        gi = bcell * Hn + colcell;
        int msub = bcell & 15; mtp = bcell >> 4;
        base_i = ((msub >> 2) * 16) * 4 + (msub & 3);
        creg = c[gi];
        bi_r = bi[colcell]; bf_r = bf[colcell];
        bg_r = bg[colcell]; bo_r = bo[colcell];
        kch = colcell >> 5; dk = colcell & 31;
        lp  = ((dk >> 3) << 4) | (bcell & 15);
    }

    __syncthreads();   // gx prologue + LDS staging complete

    const half8* wHl = (const half8*)wHs + lane;
    const half8* wLl = (const half8*)wLs + lane;

    // gx for step 0 (prefetched; later steps prefetched under the barrier)
    float gxi = 0.f, gxf = 0.f, gxg = 0.f, gxo = 0.f;
    if (tid < 256) {
        const float* gr = gx + ((size_t)0 * Bn + bcell) * 4096 + colcell;
        gxi = gr[0];    gxf = gr[1024];
        gxg = gr[2048]; gxo = gr[3072];
    }

    #pragma unroll 1
    for (int sc = 0; sc < RING; ++sc) {
        const int s = chunk * RING + sc;
        const f16* hbase = RINGM ? hRing + (size_t)s * 65536
                                 : hF + (size_t)(s & 1) * 65536;
        f16* hout = RINGM ? hRing + (size_t)(s + 1) * 65536
                          : hF + (size_t)((s + 1) & 1) * 65536;

        // hF fragment loads.
        //  RINGM: plain loads - address is fresh (never cached stale), so
        //  local L2 serves 31/32 blocks per XCD after the first fill.
        //  else: device-scope relaxed atomics (bypass stale L1/L2 -> MALL).
        half8 afr[8];
        #pragma unroll
        for (int i = 0; i < 8; ++i) {
            const int kc = kq * 8 + i;
            const f16* p = hbase + ((size_t)((kc * 4 + mt) * 64 + lane)) * 8;
            if (RINGM) {
                afr[i] = *(const half8*)p;
            } else {
                const u64* q = (const u64*)p;
                u64x2 u;
                u.x = __hip_atomic_load(q, __ATOMIC_RELAXED,
                                        __HIP_MEMORY_SCOPE_AGENT);
                u.y = __hip_atomic_load(q + 1, __ATOMIC_RELAXED,
                                        __HIP_MEMORY_SCOPE_AGENT);
                afr[i] = __builtin_bit_cast(half8, u);
            }
        }

        f32x4 accH = {0.f, 0.f, 0.f, 0.f};
        f32x4 accL = {0.f, 0.f, 0.f, 0.f};
        #pragma unroll
        for (int i = 0; i < 8; ++i) {
            const int kc = kq * 8 + i;
            half8 bh = wHl[(size_t)kc * 64];
            half8 bl = wLl[(size_t)kc * 64];
            accH = __builtin_amdgcn_mfma_f32_16x16x32_f16(afr[i], bh, accH, 0, 0, 0);
            accL = __builtin_amdgcn_mfma_f32_16x16x32_f16(afr[i], bl, accL, 0, 0, 0);
        }
        f32x4 v;
        #pragma unroll
        for (int r = 0; r < 4; ++r) v[r] = accH[r] + accL[r] * (1.0f / 2048.0f);
        *(f32x4*)&preW[wv][lane * 4] = v;
        __syncthreads();

        if (tid < 256) {
            float sg_[4];
            #pragma unroll
            for (int g = 0; g < 4; ++g) {
                int idx = base_i + (g * 4 + ducell) * 4;
                sg_[g] = preW[mtp][idx] + preW[4 + mtp][idx]
                       + preW[8 + mtp][idx] + preW[12 + mtp][idx];
            }
            float si = sg_[0] + bi_r + gxi;
            float sf = sg_[1] + bf_r + gxf;
            float sg = sg_[2] + bg_r + gxg;
            float so = sg_[3] + bo_r + gxo;
            float it = 1.f / (1.f + expf(-si));
            float ft = 1.f / (1.f + expf(-sf));
            float gt = tanhf(sg);
            float ot = 1.f / (1.f + expf(-so));
            float cn = ft * creg + it * gt;
            creg = cn;
            float hn = ot * tanhf(cn);
            // pack 4 f16 (ducell 0..3 = 4 adjacent lanes) -> one 8 B store
            union { f16 h; unsigned short u; } cv;
            cv.h = (f16)hn;
            unsigned v0 = cv.u;
            unsigned v1 = (unsigned)__shfl_down((int)v0, 1, 64);
            unsigned v2 = (unsigned)__shfl_down((int)v0, 2, 64);
            unsigned v3 = (unsigned)__shfl_down((int)v0, 3, 64);
            if (ducell == 0) {
                u64 pack = (u64)(v0 & 0xffffu) | ((u64)(v1 & 0xffffu) << 16)
                         | ((u64)(v2 & 0xffffu) << 32) | ((u64)(v3 & 0xffffu) << 48);
                u64* paddr = (u64*)(hout
                    + ((size_t)((kch * 4 + mtp) * 64 + lp)) * 8 + (dk & 7));
                __hip_atomic_store(paddr, pack, __ATOMIC_RELAXED,
                                   __HIP_MEMORY_SCOPE_AGENT);
            }
            if (s == Sn - 1) hFinal[gi] = hn;
        }

        // ---- flat barrier (skip on last step of chunk) ----
        if (sc < RING - 1) {
            asm volatile("s_waitcnt vmcnt(0)" ::: "memory");  // drain stores
            __syncthreads();
            if (tid == 0)
                __hip_atomic_fetch_add(cntArr + (((unsigned)bb & 15u) << 5), 1u,
                                       __ATOMIC_RELAXED, __HIP_MEMORY_SCOPE_AGENT);
            // prefetch next step's gx under the barrier wait
            if (tid < 256) {
                const float* gr = gx + ((size_t)(sc + 1) * Bn + bcell) * 4096
                                + colcell;
                gxi = gr[0];    gxf = gr[1024];
                gxg = gr[2048]; gxo = gr[3072];
            }
            if (wv == 0) {
                const unsigned B = (unsigned)(chunk * (RING - 1) + sc);
                const unsigned need = 256u * (B + 1u);
                while (true) {
                    unsigned pv = __hip_atomic_load(
                        cntArr + (((unsigned)lane & 15u) << 5),
                        __ATOMIC_RELAXED, __HIP_MEMORY_SCOPE_AGENT);
                    pv += (unsigned)__shfl_xor((int)pv, 1, 64);
                    pv += (unsigned)__shfl_xor((int)pv, 2, 64);
                    pv += (unsigned)__shfl_xor((int)pv, 4, 64);
                    pv += (unsigned)__shfl_xor((int)pv, 8, 64);
                    if (pv >= need) break;
                    __builtin_amdgcn_s_sleep(1);
                }
            }
            __syncthreads();
        }
    }

    if (tid < 256) c[gi] = creg;
}

// ---- tail ----
__global__ __launch_bounds__(256) void copy_hc(
    const float* __restrict__ h, const float* __restrict__ c,
    float* __restrict__ out)
{
    int i = blockIdx.x * 256 + threadIdx.x;
    out[128 + i] = h[i];
    out[128 + Bn * Hn + i] = c[i];
}

__global__ __launch_bounds__(64) void classifier(
    const float* __restrict__ h, const float* __restrict__ Vw,
    const float* __restrict__ Vb, float* __restrict__ out)
{
    int bid = blockIdx.x;
    int b = bid >> 1, n = bid & 1;
    int lane = threadIdx.x;
    float sum = 0.f;
    for (int k = lane; k < Hn; k += 64)
        sum += h[b * Hn + k] * Vw[n * Hn + k];
    #pragma unroll
    for (int off = 32; off > 0; off >>= 1)
        sum += __shfl_down(sum, off, 64);
    if (lane == 0)
        out[b * 2 + n] = sum + Vb[n];
}

// ======================= fallback (round-1 proven path) =======================

#define KT 128
#define KTP 132

__global__ __launch_bounds__(256) void lstm_step_fb(
    const int* __restrict__ x, const float* __restrict__ emb,
    const float* __restrict__ Wxi, const float* __restrict__ Wxf,
    const float* __restrict__ Wxg, const float* __restrict__ Wxo,
    const float* __restrict__ bi, const float* __restrict__ bf,
    const float* __restrict__ bg, const float* __restrict__ bo,
    const float* __restrict__ Whi, const float* __restrict__ Whf,
    const float* __restrict__ Whg, const float* __restrict__ Who,
    const float* __restrict__ h_in, const float* __restrict__ c_in,
    float* __restrict__ h_out, float* __restrict__ c_out, int s)
{
    __shared__ float sh[Bn][KTP];
    __shared__ float sw[16][KTP];
    const int tid = threadIdx.x;
    const int b = tid >> 2, j = tid & 3;
    const int cb = blockIdx.x * 4, col = cb + j;
    float acc0 = 0.f, acc1 = 0.f, acc2 = 0.f, acc3 = 0.f;

    for (int k0 = 0; k0 < En; k0 += KT) {
        for (int i = tid; i < Bn * (KT / 4); i += 256) {
            int bl = i >> 5, k4 = (i & 31) << 2;
            int tok = x[bl * Sn + s];
            *reinterpret_cast<float4*>(&sh[bl][k4]) =
                *reinterpret_cast<const float4*>(&emb[(size_t)tok * En + k0 + k4]);
        }
        for (int i = tid; i < 16 * (KT / 4); i += 256) {
            int r = i >> 5, k4 = (i & 31) << 2;
            const float* Wg = (r < 8) ? ((r < 4) ? Wxi : Wxf)
                                      : ((r < 12) ? Wxg : Wxo);
            *reinterpret_cast<float4*>(&sw[r][k4]) =
                *reinterpret_cast<const float4*>(&Wg[(size_t)(cb + (r & 3)) * En + k0 + k4]);
        }
        __syncthreads();
        #pragma unroll 8
        for (int k = 0; k < KT; k += 4) {
            float4 hv = *reinterpret_cast<const float4*>(&sh[b][k]);
            float4 w0 = *reinterpret_cast<const float4*>(&sw[j][k]);
            float4 w1 = *reinterpret_cast<const float4*>(&sw[4 + j][k]);
            float4 w2 = *reinterpret_cast<const float4*>(&sw[8 + j][k]);
            float4 w3 = *reinterpret_cast<const float4*>(&sw[12 + j][k]);
            acc0 += hv.x*w0.x + hv.y*w0.y + hv.z*w0.z + hv.w*w0.w;
            acc1 += hv.x*w1.x + hv.y*w1.y + hv.z*w1.z + hv.w*w1.w;
            acc2 += hv.x*w2.x + hv.y*w2.y + hv.z*w2.z + hv.w*w2.w;
            acc3 += hv.x*w3.x + hv.y*w3.y + hv.z*w3.z + hv.w*w3.w;
        }
        __syncthreads();
    }
    for (int k0 = 0; k0 < Hn; k0 += KT) {
        for (int i = tid; i < Bn * (KT / 4); i += 256) {
            int bl = i >> 5, k4 = (i & 31) << 2;
            *reinterpret_cast<float4*>(&sh[bl][k4]) =
                *reinterpret_cast<const float4*>(&h_in[(size_t)bl * Hn + k0 + k4]);
        }
        for (int i = tid; i < 16 * (KT / 4); i += 256) {
            int r = i >> 5, k4 = (i & 31) << 2;
            const float* Wg = (r < 8) ? ((r < 4) ? Whi : Whf)
                                      : ((r < 12) ? Whg : Who);
            *reinterpret_cast<float4*>(&sw[r][k4]) =
                *reinterpret_cast<const float4*>(&Wg[(size_t)(cb + (r & 3)) * Hn + k0 + k4]);
        }
        __syncthreads();
        #pragma unroll 8
        for (int k = 0; k < KT; k += 4) {
            float4 hv = *reinterpret_cast<const float4*>(&sh[b][k]);
            float4 w0 = *reinterpret_cast<const float4*>(&sw[j][k]);
            float4 w1 = *reinterpret_cast<const float4*>(&sw[4 + j][k]);
            float4 w2 = *reinterpret_cast<const float4*>(&sw[8 + j][k]);
            float4 w3 = *reinterpret_cast<const float4*>(&sw[12 + j][k]);
            acc0 += hv.x*w0.x + hv.y*w0.y + hv.z*w0.z + hv.w*w0.w;
            acc1 += hv.x*w1.x + hv.y*w1.y + hv.z*w1.z + hv.w*w1.w;
            acc2 += hv.x*w2.x + hv.y*w2.y + hv.z*w2.z + hv.w*w2.w;
            acc3 += hv.x*w3.x + hv.y*w3.y + hv.z*w3.z + hv.w*w3.w;
        }
        __syncthreads();
    }
    acc0 += bi[col]; acc1 += bf[col]; acc2 += bg[col]; acc3 += bo[col];
    float it = 1.f / (1.f + expf(-acc0));
    float ft = 1.f / (1.f + expf(-acc1));
    float gt = tanhf(acc2);
    float ot = 1.f / (1.f + expf(-acc3));
    float cn = ft * c_in[b * Hn + col] + it * gt;
    c_out[b * Hn + col] = cn;
    h_out[b * Hn + col] = ot * tanhf(cn);
}

// ======================= launcher =======================

extern "C" void kernel_launch(void* const* d_in, const int* in_sizes, int n_in,
                              void* d_out, int out_size, void* d_ws, size_t ws_size,
                              hipStream_t stream) {
    const int*   x   = (const int*)  d_in[0];
    const float* emb = (const float*)d_in[1];
    const float* Wxi = (const float*)d_in[2];
    const float* bi  = (const float*)d_in[3];
    const float* Whi = (const float*)d_in[4];
    const float* Wxf = (const float*)d_in[5];
    const float* bf  = (const float*)d_in[6];
    const float* Whf = (const float*)d_in[7];
    const float* Wxg = (const float*)d_in[8];
    const float* bg  = (const float*)d_in[9];
    const float* Whg = (const float*)d_in[10];
    const float* Wxo = (const float*)d_in[11];
    const float* bo  = (const float*)d_in[12];
    const float* Who = (const float*)d_in[13];
    const float* Vw  = (const float*)d_in[14];
    const float* Vb  = (const float*)d_in[15];
    float* out = (float*)d_out;

    // ws: [hF 256K][c 256K][h 256K][eF 32M][wpHi 12M][wpLo 12M][gx 32M]
    //     [cnt 4K][hRing 67.2M]
    const size_t szHF   = (size_t)2 * 65536 * sizeof(f16);              // 256 KB
    const size_t szC    = (size_t)Bn * Hn * sizeof(float);              // 256 KB
    const size_t szEF   = (size_t)Sn * 16 * 4 * 64 * 8 * sizeof(f16);   // 32 MB
    const size_t szWp   = (size_t)256 * 48 * 64 * 8 * sizeof(f16);      // 12 MB
    const size_t szGx   = (size_t)RING * Bn * 4096 * sizeof(float);     // 32 MB
    const size_t szRing = (size_t)(Sn + 1) * 65536 * sizeof(f16);       // 67.2 MB
    const size_t need_mid  = szHF + 2 * szC + szEF + 2 * szWp;
    const size_t need_gx   = need_mid + szGx;
    const size_t need_coop = need_gx + 4096;
    const size_t need_ring = need_coop + szRing;

    if (ws_size >= need_mid) {
        const bool haveGx   = (ws_size >= need_gx);
        const bool haveCoop = (ws_size >= need_coop);
        const bool haveRing = (ws_size >= need_ring);
        char* base = (char*)d_ws;
        f16*   hF   = (f16*)base;   base += szHF;
        float* c    = (float*)base; base += szC;
        float* h    = (float*)base; base += szC;
        f16*   eF   = (f16*)base;   base += szEF;
        f16*   wpHi = (f16*)base;   base += szWp;
        f16*   wpLo = (f16*)base;   base += szWp;
        float* gx   = (float*)base; base += szGx;
        unsigned* cnt = (unsigned*)base; base += 4096;
        f16*   hRing = (f16*)base;

        hipMemsetAsync(d_ws, 0, szHF + szC, stream);   // hF both bufs + c
        if (haveCoop) hipMemsetAsync(cnt, 0, 4096, stream);  // arrival lines
        if (haveRing) hipMemsetAsync(hRing, 0, 65536 * sizeof(f16), stream);
        wpack_kernel<<<dim3(3072), dim3(256), 0, stream>>>(
            Whi, Whf, Whg, Who, Wxi, Wxf, Wxg, Wxo, wpHi, wpLo);
        epack_kernel<<<dim3(8192), dim3(256), 0, stream>>>(x, emb, eF);

        if (haveGx) {
            bool coop = haveCoop;
            for (int chunk = 0; chunk < Sn / RING; ++chunk) {
                if (coop) {
                    f16* hFp = hF;
                    f16* hRp = hRing;
                    const half8* eF8   = (const half8*)eF;
                    const half8* wpHi8 = (const half8*)wpHi;
                    const half8* wpLo8 = (const half8*)wpLo;
                    float* gxp = gx;
                    const float* bip = bi; const float* bfp = bf;
                    const float* bgp = bg; const float* bop = bo;
                    float* cp = c; float* hp = h;
                    unsigned* cntp = cnt;
                    int ci = chunk;
                    void* args[] = { &hFp, &hRp, &eF8, &wpHi8, &wpLo8, &gxp,
                                     &bip, &bfp, &bgp, &bop, &cp, &hp,
                                     &cntp, &ci };
                    const void* fn = haveRing
                        ? (const void*)steps_chunk_coop<true>
                        : (const void*)steps_chunk_coop<false>;
                    hipError_t e = hipLaunchCooperativeKernel(
                        fn, dim3(NBLK), dim3(1024), args, 0, stream);
                    if (e != hipSuccess) { coop = false; (void)hipGetLastError(); }
                }
                if (!coop) {
                    gx_chunk_kernel<<<dim3(2048), dim3(256), 0, stream>>>(
                        (const half8*)eF, (const half8*)wpHi, (const half8*)wpLo,
                        gx, chunk);
                    for (int sc = 0; sc < RING; ++sc) {
                        int s = chunk * RING + sc;
                        const f16* hin  = hF + (size_t)(s & 1) * 65536;
                        f16*       hout = hF + (size_t)((s + 1) & 1) * 65536;
                        step_kernel<true><<<dim3(256), dim3(1024), 0, stream>>>(
                            hin, hout, (const half8*)eF,
                            (const half8*)wpHi, (const half8*)wpLo,
                            gx, bi, bf, bg, bo, c, h, s);
                    }
                }
            }
        } else {
            for (int s = 0; s < Sn; ++s) {
                const f16* hin  = hF + (size_t)(s & 1) * 65536;
                f16*       hout = hF + (size_t)((s + 1) & 1) * 65536;
                step_kernel<false><<<dim3(256), dim3(1024), 0, stream>>>(
                    hin, hout, (const half8*)eF,
                    (const half8*)wpHi, (const half8*)wpLo,
                    (const float*)nullptr, bi, bf, bg, bo, c, h, s);
            }
        }
        copy_hc<<<dim3(Bn * Hn / 256), dim3(256), 0, stream>>>(h, c, out);
        classifier<<<dim3(Bn * 2), dim3(64), 0, stream>>>(h, Vw, Vb, out);
    } else {
        float* hA = (float*)d_ws;
        float* cA = hA + Bn * Hn;
        float* hB = cA + Bn * Hn;
        float* cB = hB + Bn * Hn;
        hipMemsetAsync(d_ws, 0, (size_t)2 * Bn * Hn * sizeof(float), stream);
        for (int s = 0; s < Sn; ++s) {
            const float* hi = (s & 1) ? hB : hA;
            const float* ci = (s & 1) ? cB : cA;
            float* ho = (s & 1) ? hA : hB;
            float* co = (s & 1) ? cA : cB;
            lstm_step_fb<<<dim3(Hn / 4), dim3(256), 0, stream>>>(
                x, emb, Wxi, Wxf, Wxg, Wxo, bi, bf, bg, bo,
                Whi, Whf, Whg, Who, hi, ci, ho, co, s);
        }
        copy_hc<<<dim3(Bn * Hn / 256), dim3(256), 0, stream>>>(hA, cA, out);
        classifier<<<dim3(Bn * 2), dim3(64), 0, stream>>>(hA, Vw, Vb, out);
    }
}